// Round 8
// baseline (243.914 us; speedup 1.0000x reference)
//
#include <hip/hip_runtime.h>

// MiniAttentionLayer fused kernel for MI355X (gfx950).
//
// ROUND 8 (bisect): R6/R7 failed with garbage-scale, run-varying absmax while
// all index maps verify by inspection. This round restores the R5 fused kernel
// VERBATIM (proven pass @140us: phase1 scores, Qm/vbar phase2, phase3) and
// feeds it from the fast gemm4 prep chain (F->FT, P, A2=F_h^T@Wk_h,
// M=A2@W*_k, Qm=P_h@Wv_h, tiled casts). PASS => R6 bug is in the G-path.
// FAIL => bug is in the gemm4/M-chain preps.
//
//   score[h,s]*16 = x_e^T M_{h,s} x_s ; softmax -> attn
//   M^n_h = A_h @ Wn_k ; M^e_h = A_h @ We_k ; A_h = F_h^T @ Wk_h ; F = Wq@We_q
//   vbar_h = sum_s attn[h,s] v_s ; v_s = W*_v x_s (+ b*_v)
//   h1pre = Qm @ [vbar_0|vbar_1] + c2 ; Qm_h = P @ Wv_h ; P = W1@Wo
//   out = W2 @ silu(h1pre) + b2

#define TPB 256

typedef __attribute__((ext_vector_type(8))) short bf16x8;
typedef __attribute__((ext_vector_type(4))) float f32x4;

__device__ __forceinline__ unsigned short f2bf(float f) {
  union { float f; unsigned u; } v; v.f = f;
  unsigned r = v.u + 0x7FFFu + ((v.u >> 16) & 1u);  // RNE
  return (unsigned short)(r >> 16);
}
__device__ __forceinline__ float bf2f(unsigned short h) {
  union { unsigned u; float f; } v; v.u = ((unsigned)h) << 16;
  return v.f;
}
__device__ __forceinline__ f32x4 mfma16(bf16x8 a, bf16x8 b, f32x4 c) {
  return __builtin_amdgcn_mfma_f32_16x16x32_bf16(a, b, c, 0, 0, 0);
}
__device__ __forceinline__ bf16x8 pack8(const float* __restrict__ p) {
  float4 a = *(const float4*)p;
  float4 b = *(const float4*)(p + 4);
  bf16x8 r;
  r[0] = (short)f2bf(a.x); r[1] = (short)f2bf(a.y);
  r[2] = (short)f2bf(a.z); r[3] = (short)f2bf(a.w);
  r[4] = (short)f2bf(b.x); r[5] = (short)f2bf(b.y);
  r[6] = (short)f2bf(b.z); r[7] = (short)f2bf(b.w);
  return r;
}
// fragment-tiled offset: element (lr = B-col within 16-tile, k) -> tiled index
__device__ __forceinline__ int fragoff(int lr, int k) {
  return (k >> 5) * 512 + ((k >> 3) & 3) * 128 + lr * 8 + (k & 7);
}

// GEMM micro-tile: 4 outputs along m per thread. acc[i] += sum_k A[m0+i][k]*B[k][n].
__device__ __forceinline__ void gemm4(const float* __restrict__ A0, int lda,
                                      const float* __restrict__ Bp, int ldb,
                                      int K, float (&acc)[4]) {
  for (int k = 0; k < K; k += 4) {
    float4 x0 = *(const float4*)(A0 + k);
    float4 x1 = *(const float4*)(A0 + lda + k);
    float4 x2 = *(const float4*)(A0 + 2 * lda + k);
    float4 x3 = *(const float4*)(A0 + 3 * lda + k);
    float b0 = Bp[(size_t)k * ldb];
    float b1 = Bp[(size_t)(k + 1) * ldb];
    float b2 = Bp[(size_t)(k + 2) * ldb];
    float b3 = Bp[(size_t)(k + 3) * ldb];
    acc[0] += x0.x * b0; acc[1] += x1.x * b0; acc[2] += x2.x * b0; acc[3] += x3.x * b0;
    acc[0] += x0.y * b1; acc[1] += x1.y * b1; acc[2] += x2.y * b1; acc[3] += x3.y * b1;
    acc[0] += x0.z * b2; acc[1] += x1.z * b2; acc[2] += x2.z * b2; acc[3] += x3.z * b2;
    acc[0] += x0.w * b3; acc[1] += x1.w * b3; acc[2] += x2.w * b3; acc[3] += x3.w * b3;
  }
}

// ---------------------------------------------------------------------------
// prep1: FT = (Wq@We_q)^T ; P = W1@Wo ; WnvT/WevT/W2bT tiled bf16 casts.
// ---------------------------------------------------------------------------
__global__ void prep1(const float* __restrict__ Wn, const float* __restrict__ We,
                      const float* __restrict__ Wi, const float* __restrict__ Wo,
                      const float* __restrict__ W1, const float* __restrict__ W2,
                      float* __restrict__ FT, float* __restrict__ P,
                      unsigned short* __restrict__ WnvT, unsigned short* __restrict__ WevT,
                      unsigned short* __restrict__ W2bT) {
  const int bid = blockIdx.x, tid = threadIdx.x;
  if (bid < 64) {                         // F [512 m, 128 n] K=512 -> FT[n][m]
    int m0 = bid * 8 + (tid >> 7) * 4, n = tid & 127;
    float acc[4] = {0.f, 0.f, 0.f, 0.f};
    gemm4(Wi + m0 * 512, 512, We + n, 128, 512, acc);
#pragma unroll
    for (int i = 0; i < 4; ++i) FT[n * 512 + m0 + i] = acc[i];
  } else if (bid < 192) {                 // P [256,512] K=512
    int b = bid - 64; int m0 = (b >> 1) * 4, n = (b & 1) * 256 + tid;
    float acc[4] = {0.f, 0.f, 0.f, 0.f};
    gemm4(W1 + m0 * 512, 512, Wo + n, 512, 512, acc);
#pragma unroll
    for (int i = 0; i < 4; ++i) P[(m0 + i) * 512 + n] = acc[i];
  } else if (bid < 320) {                 // Wn_v -> bf16 TILED: [32 chunks][kt 8][lane 64][8]
    int i = ((bid - 192) * 256 + tid) * 4;
#pragma unroll
    for (int t = 0; t < 4; ++t) {
      int ii = i + t; int vrow = ii >> 8, k = ii & 255;
      WnvT[(vrow >> 4) * 4096 + fragoff(vrow & 15, k)] = f2bf(Wn[262144 + ii]);
    }
  } else if (bid < 384) {                 // We_v -> bf16 TILED: [32][kt 4][64][8]
    int i = ((bid - 320) * 256 + tid) * 4;
#pragma unroll
    for (int t = 0; t < 4; ++t) {
      int ii = i + t; int vrow = ii >> 7, k = ii & 127;
      WevT[(vrow >> 4) * 2048 + fragoff(vrow & 15, k)] = f2bf(We[131072 + ii]);
    }
  } else {                                // W2 -> bf16 TILED: [kg 4][p 2][ot 8][64][8]
    int i = ((bid - 384) * 256 + tid) * 4;
#pragma unroll
    for (int t = 0; t < 4; ++t) {
      int ii = i + t; int o = ii >> 8, k = ii & 255;
      W2bT[(k >> 6) * 8192 + ((k >> 5) & 1) * 4096 + (o >> 4) * 512 + fragoff(o & 15, k & 31)] =
          f2bf(W2[ii]);
    }
  }
}

// ---------------------------------------------------------------------------
// prep2: A_h = F_h^T @ Wk_h ; QmT_h = P_h @ Wv_h (bf16 tiled, R5 layout) ; c2.
// ---------------------------------------------------------------------------
__global__ void prep2(const float* __restrict__ Wi, const float* __restrict__ W1,
                      const float* __restrict__ bi, const float* __restrict__ bo,
                      const float* __restrict__ b1,
                      const float* __restrict__ FT, const float* __restrict__ P,
                      float* __restrict__ A2, unsigned short* __restrict__ QmT,
                      float* __restrict__ c2) {
  const int bid = blockIdx.x, tid = threadIdx.x;
  if (bid < 128) {                        // A_h [128 a, 512 k] K=256 (c)
    int h = bid >> 6, r = bid & 63;
    int m0 = (r >> 1) * 4, n = (r & 1) * 256 + tid;
    float acc[4] = {0.f, 0.f, 0.f, 0.f};
    gemm4(FT + m0 * 512 + h * 256, 512, Wi + (size_t)(512 + h * 256) * 512 + n, 512, 256, acc);
#pragma unroll
    for (int i = 0; i < 4; ++i) A2[h * 65536 + (m0 + i) * 512 + n] = acc[i];
  } else if (bid < 384) {                 // Qm_h[i 256][t 512] K=256 (c), R5 tiled store
    int b = bid - 128; int h = b >> 7, r = b & 127;
    int m0 = (r >> 1) * 4, n = (r & 1) * 256 + tid;
    float acc[4] = {0.f, 0.f, 0.f, 0.f};
    gemm4(P + m0 * 512 + h * 256, 512, Wi + (size_t)(1024 + h * 256) * 512 + n, 512, 256, acc);
#pragma unroll
    for (int i = 0; i < 4; ++i) {
      int m = m0 + i;
      QmT[(n >> 5) * 16384 + h * 8192 + (m >> 4) * 512 + fragoff(m & 15, n & 31)] = f2bf(acc[i]);
    }
  } else {                                // c2 (one block): b1 + P@bv + W1@bo
    float cc = b1[tid];
    for (int c = 0; c < 512; ++c) cc += P[tid * 512 + c] * bi[1024 + c] + W1[tid * 512 + c] * bo[c];
    c2[tid] = cc;
  }
}

// ---------------------------------------------------------------------------
// prep3: MtnT = A_h @ Wn_k, MteT = A_h @ We_k (bf16 tiled, R5 layout).
// ---------------------------------------------------------------------------
__global__ void prep3(const float* __restrict__ Wn, const float* __restrict__ We,
                      const float* __restrict__ A2,
                      unsigned short* __restrict__ MtnT, unsigned short* __restrict__ MteT) {
  const int bid = blockIdx.x, tid = threadIdx.x;
  if (bid < 64) {                         // Mn_h [128 a, 256 b] K=512
    int h = bid >> 5, m0 = (bid & 31) * 4, n = tid;
    float acc[4] = {0.f, 0.f, 0.f, 0.f};
    gemm4(A2 + h * 65536 + m0 * 512, 512, Wn + 512 * 256 + n, 256, 512, acc);
#pragma unroll
    for (int i = 0; i < 4; ++i) {
      int a = m0 + i;
      MtnT[(h * 2 + (n >> 7)) * 16384 + ((n >> 5) & 3) * 4096 + ((n >> 4) & 1) * 2048 +
           fragoff(n & 15, a)] = f2bf(acc[i]);
    }
  } else {                                // Me_h [128 a, 128 b] K=512
    int b = bid - 64; int h = b >> 4, m0 = (b & 15) * 8 + (tid >> 7) * 4, n = tid & 127;
    float acc[4] = {0.f, 0.f, 0.f, 0.f};
    gemm4(A2 + h * 65536 + m0 * 512, 512, We + 512 * 128 + n, 128, 512, acc);
#pragma unroll
    for (int i = 0; i < 4; ++i) {
      int a = m0 + i;
      MteT[h * 16384 + ((n >> 5) & 3) * 4096 + ((n >> 4) & 1) * 2048 + fragoff(n & 15, a)] =
          f2bf(acc[i]);
    }
  }
}

// ---------------------------------------------------------------------------
// Fused kernel helpers (R5 VERBATIM from here down)
// ---------------------------------------------------------------------------
__device__ __forceinline__ void stage32k(unsigned short* lds, const unsigned short* __restrict__ src,
                                         int tid) {
#pragma unroll
  for (int i = 0; i < 8; ++i) {
    int seg = i * 256 + tid;
    *(int4*)(lds + seg * 8) = *(const int4*)(src + seg * 8);
  }
}

template <int AOFS>
__device__ __forceinline__ void p1n(const unsigned short* __restrict__ srcT,
                                    unsigned short* sflat, unsigned short (&tb)[16][40],
                                    const bf16x8 (&au)[8], const bf16x8 (&av)[8],
                                    const bf16x8 (&ae)[4], int tid, int lrow, int lgrp,
                                    float& su, float& sv) {
  stage32k(sflat, srcT, tid);
  __syncthreads();
  const int lane8 = (lgrp * 16 + lrow) * 8;
#pragma unroll
  for (int c = 0; c < 4; ++c) {
    f32x4 acc0 = {0.f, 0.f, 0.f, 0.f}, acc1 = {0.f, 0.f, 0.f, 0.f};
#pragma unroll
    for (int kt = 0; kt < 4; ++kt) {
      bf16x8 b0 = *(bf16x8*)(sflat + c * 4096 + kt * 512 + lane8);
      bf16x8 b1f = *(bf16x8*)(sflat + c * 4096 + 2048 + kt * 512 + lane8);
      acc0 = mfma16(ae[kt], b0, acc0);
      acc1 = mfma16(ae[kt], b1f, acc1);
    }
#pragma unroll
    for (int j = 0; j < 4; ++j) {
      tb[lgrp * 4 + j][lrow] = f2bf(acc0[j]);
      tb[lgrp * 4 + j][16 + lrow] = f2bf(acc1[j]);
    }
    bf16x8 y = *(bf16x8*)&tb[lrow][lgrp * 8];
#pragma unroll
    for (int j = 0; j < 8; ++j) {
      float yf = bf2f((unsigned short)y[j]);
      su += yf * bf2f((unsigned short)au[AOFS + c][j]);
      sv += yf * bf2f((unsigned short)av[AOFS + c][j]);
    }
  }
  __syncthreads();
}

__device__ __forceinline__ void p1e(const unsigned short* __restrict__ srcT,
                                    unsigned short* sflat, unsigned short (&tb)[16][40],
                                    const bf16x8 (&ae)[4], int tid, int lrow, int lgrp,
                                    float& se) {
  stage32k(sflat, srcT, tid);
  __syncthreads();
  const int lane8 = (lgrp * 16 + lrow) * 8;
#pragma unroll
  for (int c = 0; c < 4; ++c) {
    f32x4 acc0 = {0.f, 0.f, 0.f, 0.f}, acc1 = {0.f, 0.f, 0.f, 0.f};
#pragma unroll
    for (int kt = 0; kt < 4; ++kt) {
      bf16x8 b0 = *(bf16x8*)(sflat + c * 4096 + kt * 512 + lane8);
      bf16x8 b1f = *(bf16x8*)(sflat + c * 4096 + 2048 + kt * 512 + lane8);
      acc0 = mfma16(ae[kt], b0, acc0);
      acc1 = mfma16(ae[kt], b1f, acc1);
    }
#pragma unroll
    for (int j = 0; j < 4; ++j) {
      tb[lgrp * 4 + j][lrow] = f2bf(acc0[j]);
      tb[lgrp * 4 + j][16 + lrow] = f2bf(acc1[j]);
    }
    bf16x8 y = *(bf16x8*)&tb[lrow][lgrp * 8];
#pragma unroll
    for (int j = 0; j < 8; ++j)
      se += bf2f((unsigned short)y[j]) * bf2f((unsigned short)ae[c][j]);
  }
  __syncthreads();
}

// ---------------------------------------------------------------------------
// Fused main kernel: 512 blocks x 256 threads (4 waves x 16 rows). R5 VERBATIM.
// ---------------------------------------------------------------------------
__global__ __launch_bounds__(TPB, 1) void fused_kernel(
    const float* __restrict__ Xu, const float* __restrict__ Xv, const float* __restrict__ Xe,
    const float* __restrict__ bn, const float* __restrict__ be, const float* __restrict__ b2,
    const unsigned short* __restrict__ MtnT, const unsigned short* __restrict__ MteT,
    const unsigned short* __restrict__ WnvT, const unsigned short* __restrict__ WevT,
    const unsigned short* __restrict__ QmT, const unsigned short* __restrict__ W2bT,
    const float* __restrict__ c2, float* __restrict__ Out) {
  // buf b at sStage + b*14336: Wnv[0,4096) Wev[4096,6144) Qm-half[6144,14336)
  __shared__ unsigned short sStage[28672];          // 56 KB
  __shared__ unsigned short sTbuf[4][2][16][40];    // 10 KB wave-local bounce
  __shared__ float sAttn[4][16][8];                 // 2 KB

  const int tid = threadIdx.x;
  const int wave = tid >> 6;
  const int lane = tid & 63;
  const int lrow = lane & 15, lgrp = lane >> 4;
  const int lane8 = lane * 8;
  const int r0 = blockIdx.x * 64 + wave * 16;

  // ---- A fragments (rows of this wave), fp32 -> bf16 ----
  bf16x8 au[8], av[8], ae[4];
  {
    const float* xu = Xu + (size_t)(r0 + lrow) * 256;
    const float* xv = Xv + (size_t)(r0 + lrow) * 256;
    const float* xe = Xe + (size_t)(r0 + lrow) * 128;
#pragma unroll
    for (int kt = 0; kt < 8; ++kt) {
      int off = kt * 32 + lgrp * 8;
      au[kt] = pack8(xu + off);
      av[kt] = pack8(xv + off);
    }
#pragma unroll
    for (int kt = 0; kt < 4; ++kt) ae[kt] = pack8(xe + kt * 32 + lgrp * 8);
  }

  // ================= Phase 1: scores (6 staged 32KB slices) =================
  float su0 = 0.f, sv0 = 0.f, se0 = 0.f, su1 = 0.f, sv1 = 0.f, se1 = 0.f;
  p1n<0>(MtnT,          sStage, sTbuf[wave][0], au, av, ae, tid, lrow, lgrp, su0, sv0);
  p1n<4>(MtnT + 16384,  sStage, sTbuf[wave][0], au, av, ae, tid, lrow, lgrp, su0, sv0);
  p1n<0>(MtnT + 32768,  sStage, sTbuf[wave][0], au, av, ae, tid, lrow, lgrp, su1, sv1);
  p1n<4>(MtnT + 49152,  sStage, sTbuf[wave][0], au, av, ae, tid, lrow, lgrp, su1, sv1);
  p1e(MteT,          sStage, sTbuf[wave][0], ae, tid, lrow, lgrp, se0);
  p1e(MteT + 16384,  sStage, sTbuf[wave][0], ae, tid, lrow, lgrp, se1);

  su0 += __shfl_xor(su0, 16); su0 += __shfl_xor(su0, 32);
  sv0 += __shfl_xor(sv0, 16); sv0 += __shfl_xor(sv0, 32);
  se0 += __shfl_xor(se0, 16); se0 += __shfl_xor(se0, 32);
  su1 += __shfl_xor(su1, 16); su1 += __shfl_xor(su1, 32);
  sv1 += __shfl_xor(sv1, 16); sv1 += __shfl_xor(sv1, 32);
  se1 += __shfl_xor(se1, 16); se1 += __shfl_xor(se1, 32);
  if (lane < 16) {
    sAttn[wave][lrow][0] = su0; sAttn[wave][lrow][1] = sv0; sAttn[wave][lrow][2] = se0;
    sAttn[wave][lrow][3] = su1; sAttn[wave][lrow][4] = sv1; sAttn[wave][lrow][5] = se1;
  }
  // softmax over s (scale 1/16); wave-local
  if (lane < 16) {
#pragma unroll
    for (int h = 0; h < 2; ++h) {
      float s0 = sAttn[wave][lrow][h * 3 + 0] * 0.0625f;
      float s1 = sAttn[wave][lrow][h * 3 + 1] * 0.0625f;
      float s2 = sAttn[wave][lrow][h * 3 + 2] * 0.0625f;
      float m = fmaxf(s0, fmaxf(s1, s2));
      float e0 = __expf(s0 - m), e1 = __expf(s1 - m), e2 = __expf(s2 - m);
      float inv = 1.f / (e0 + e1 + e2);
      sAttn[wave][lrow][h * 3 + 0] = e0 * inv;
      sAttn[wave][lrow][h * 3 + 1] = e1 * inv;
      sAttn[wave][lrow][h * 3 + 2] = e2 * inv;
    }
  }

  // ================= Phase 2: v-GEMM + vbar + Q-GEMM, 32 staged chunks ======
  f32x4 h1acc[16];
#pragma unroll
  for (int i = 0; i < 16; ++i) h1acc[i] = (f32x4){0.f, 0.f, 0.f, 0.f};

  // prologue: buf0 = {Wnv(0), Wev(0), Qm pair0 half1}
  {
#pragma unroll
    for (int i = 0; i < 7; ++i) {
      int seg = i * 256 + tid;
      int4 v;
      if (i < 2)       v = *(const int4*)(WnvT + seg * 8);
      else if (i == 2) v = *(const int4*)(WevT + (seg - 512) * 8);
      else             v = *(const int4*)(QmT + 8192 + (seg - 768) * 8);
      *(int4*)(sStage + seg * 8) = v;
    }
  }
  __syncthreads();

#pragma unroll 2
  for (int t = 0; t < 32; ++t) {
    const int cur = t & 1;
    unsigned short* wb = sStage + cur * 14336;
    unsigned short* nb = sStage + (cur ^ 1) * 14336;

    // T14: issue prefetch loads for chunk t+1 (clamped at the end, harmless dup)
    const int cn = (t < 31) ? (t + 1) : 31;
    int qp = cur ? ((t + 1) >> 1) : (t >> 1);
    if (qp > 15) qp = 15;
    const int qoff = qp * 16384 + cur * 8192;
    int4 st0 = *(const int4*)(WnvT + cn * 4096 + tid * 8);
    int4 st1 = *(const int4*)(WnvT + cn * 4096 + (256 + tid) * 8);
    int4 st2 = *(const int4*)(WevT + cn * 2048 + tid * 8);
    int4 st3 = *(const int4*)(QmT + qoff + tid * 8);
    int4 st4 = *(const int4*)(QmT + qoff + (256 + tid) * 8);
    int4 st5 = *(const int4*)(QmT + qoff + (512 + tid) * 8);
    int4 st6 = *(const int4*)(QmT + qoff + (768 + tid) * 8);

    // v-GEMM for this chunk's 16 v-cols
    f32x4 vu = {0.f, 0.f, 0.f, 0.f}, vv = {0.f, 0.f, 0.f, 0.f}, ve = {0.f, 0.f, 0.f, 0.f};
#pragma unroll
    for (int kt = 0; kt < 8; ++kt) {
      bf16x8 b = *(bf16x8*)(wb + kt * 512 + lane8);
      vu = mfma16(au[kt], b, vu);
      vv = mfma16(av[kt], b, vv);
    }
#pragma unroll
    for (int kt = 0; kt < 4; ++kt) {
      bf16x8 b = *(bf16x8*)(wb + 4096 + kt * 512 + lane8);
      ve = mfma16(ae[kt], b, ve);
    }
    const int vrow = t * 16 + lrow;
    const float bnv = bn[1024 + vrow], bev = be[1024 + vrow];
#pragma unroll
    for (int j = 0; j < 4; ++j) {
      const float* ar = &sAttn[wave][lgrp * 4 + j][0];
#pragma unroll
      for (int h = 0; h < 2; ++h) {
        float a0 = ar[h * 3 + 0], a1 = ar[h * 3 + 1], a2 = ar[h * 3 + 2];
        float vb = a0 * vu[j] + a1 * vv[j] + a2 * ve[j] + (a0 + a1) * bnv + a2 * bev;
        sTbuf[wave][h][lgrp * 4 + j][cur * 16 + lrow] = f2bf(vb);
      }
    }

    if (cur) {  // odd chunk: Q-GEMM over the completed 32-col pair
#pragma unroll
      for (int h2 = 0; h2 < 2; ++h2) {
        const unsigned short* qb = (h2 == 0 ? wb : nb) + 6144;
        bf16x8 vbx = *(bf16x8*)&sTbuf[wave][h2][lrow][lgrp * 8];
#pragma unroll
        for (int nt = 0; nt < 16; ++nt) {
          bf16x8 bq = *(bf16x8*)(qb + nt * 512 + lane8);
          h1acc[nt] = mfma16(vbx, bq, h1acc[nt]);
        }
      }
      __syncthreads();  // all waves done reading nb's Qm slot before overwrite
    }

    // write prefetched chunk t+1 into the other buffer
    *(int4*)(nb + tid * 8) = st0;
    *(int4*)(nb + (256 + tid) * 8) = st1;
    *(int4*)(nb + (512 + tid) * 8) = st2;
    *(int4*)(nb + (768 + tid) * 8) = st3;
    *(int4*)(nb + (1024 + tid) * 8) = st4;
    *(int4*)(nb + (1280 + tid) * 8) = st5;
    *(int4*)(nb + (1536 + tid) * 8) = st6;
    __syncthreads();
  }

  // ================= Phase 3: silu + W2 (2 staged 32KB halves) ==============
  f32x4 outacc[8];
#pragma unroll
  for (int i = 0; i < 8; ++i) outacc[i] = (f32x4){0.f, 0.f, 0.f, 0.f};

#pragma unroll
  for (int hh = 0; hh < 2; ++hh) {
    if (hh) __syncthreads();  // protect previous half's reads
    stage32k(sStage, W2bT + hh * 16384, tid);
    __syncthreads();
#pragma unroll
    for (int kc = 0; kc < 2; ++kc) {
      const int kg = hh * 2 + kc;
#pragma unroll
      for (int tt = 0; tt < 4; ++tt) {
        int nt = kg * 4 + tt;
        float c2v = c2[nt * 16 + lrow];
#pragma unroll
        for (int j = 0; j < 4; ++j) {
          float x = h1acc[nt][j] + c2v;
          float s = x / (1.f + __expf(-x));  // silu
          sTbuf[wave][tt >> 1][lgrp * 4 + j][(tt & 1) * 16 + lrow] = f2bf(s);
        }
      }
#pragma unroll
      for (int p = 0; p < 2; ++p) {
        bf16x8 hA = *(bf16x8*)&sTbuf[wave][p][lrow][lgrp * 8];
#pragma unroll
        for (int ot = 0; ot < 8; ++ot) {
          bf16x8 w2 = *(bf16x8*)(sStage + kc * 8192 + p * 4096 + ot * 512 + lane8);
          outacc[ot] = mfma16(hA, w2, outacc[ot]);
        }
      }
    }
  }

  // epilogue: out = outacc + b2 (fp32)
#pragma unroll
  for (int ot = 0; ot < 8; ++ot) {
    int col = ot * 16 + lrow;
    float b2v = b2[col];
#pragma unroll
    for (int j = 0; j < 4; ++j)
      Out[(size_t)(r0 + lgrp * 4 + j) * 128 + col] = outacc[ot][j] + b2v;
  }
}

// ---------------------------------------------------------------------------
extern "C" void kernel_launch(void* const* d_in, const int* in_sizes, int n_in,
                              void* d_out, int out_size, void* d_ws, size_t ws_size,
                              hipStream_t stream) {
  const float* Xu = (const float*)d_in[0];
  const float* Xv = (const float*)d_in[1];
  const float* Xe = (const float*)d_in[2];
  const float* Wn = (const float*)d_in[3];
  const float* bn = (const float*)d_in[4];
  const float* We = (const float*)d_in[5];
  const float* be = (const float*)d_in[6];
  const float* Wi = (const float*)d_in[7];
  const float* bi = (const float*)d_in[8];
  const float* Wo = (const float*)d_in[9];
  const float* bo = (const float*)d_in[10];
  const float* W1 = (const float*)d_in[11];
  const float* b1 = (const float*)d_in[12];
  const float* W2 = (const float*)d_in[13];
  const float* b2 = (const float*)d_in[14];

  // ws layout, NO aliasing; high-water 2,491,392 B < R5-proven 2,753,536 B.
  char* ws = (char*)d_ws;
  float* FT = (float*)(ws + 0);                            // [128,512] f32
  float* P  = (float*)(ws + 262144);                       // [256,512] f32
  float* A2 = (float*)(ws + 786432);                       // [2][128,512] f32
  unsigned short* QmT  = (unsigned short*)(ws + 1310720);  // 262144 bf16 tiled (R5 layout)
  unsigned short* WnvT = (unsigned short*)(ws + 1835008);  // 131072 bf16 tiled
  unsigned short* WevT = (unsigned short*)(ws + 2097152);  // 65536 bf16 tiled
  unsigned short* MtnT = (unsigned short*)(ws + 2228224);  // 65536 bf16 tiled
  unsigned short* MteT = (unsigned short*)(ws + 2359296);  // 32768 bf16 tiled
  unsigned short* W2bT = (unsigned short*)(ws + 2424832);  // 32768 bf16 tiled
  float* c2 = (float*)(ws + 2490368);                      // [256] f32

  prep1<<<416, 256, 0, stream>>>(Wn, We, Wi, Wo, W1, W2, FT, P, WnvT, WevT, W2bT);
  prep2<<<385, 256, 0, stream>>>(Wi, W1, bi, bo, b1, FT, P, A2, QmT, c2);
  prep3<<<96, 256, 0, stream>>>(Wn, We, A2, MtnT, MteT);
  fused_kernel<<<512, 256, 0, stream>>>(Xu, Xv, Xe, bn, be, b2, MtnT, MteT, WnvT, WevT, QmT, W2bT,
                                        c2, (float*)d_out);
}

// Round 9
// 214.525 us; speedup vs baseline: 1.1370x; 1.1370x over previous
//
#include <hip/hip_runtime.h>

// MiniAttentionLayer fused kernel for MI355X (gfx950).
//
// ROUND 9: R8 bisect PASSED -> gemm preps + R5-fused are correct; G-path is
// quarantined. This round: preps rebuilt with a 4x4 micro-tile (16 out/thread,
// all-float4 loads, 64 FMA per 8 loads, 16 indep chains) and re-associated to
// TWO launches: prep1 {F, P, Kn=Wk_h@Wn_k, Ke=Wk_h@We_k, casts},
// prep2 {Mtn=F_h^T@Kn, Mte=F_h^T@Ke, Qm=P_h@Wv_h, c2}. Fused kernel is R8
// VERBATIM. ws repack = exactly 2,753,536 B (the R5/R8-proven ceiling).
//
//   score[h,s]*16 = x_e^T M_{h,s} x_s ; softmax -> attn
//   M^n_h = F_h^T @ (Wk_h @ Wn_k) ; M^e_h = F_h^T @ (Wk_h @ We_k) ; F = Wq@We_q
//   vbar_h = sum_s attn[h,s] v_s ; v_s = W*_v x_s (+ b*_v)
//   h1pre = Qm @ [vbar_0|vbar_1] + c2 ; Qm_h = P @ Wv_h ; P = W1@Wo
//   out = W2 @ silu(h1pre) + b2

#define TPB 256

typedef __attribute__((ext_vector_type(8))) short bf16x8;
typedef __attribute__((ext_vector_type(4))) float f32x4;

__device__ __forceinline__ unsigned short f2bf(float f) {
  union { float f; unsigned u; } v; v.f = f;
  unsigned r = v.u + 0x7FFFu + ((v.u >> 16) & 1u);  // RNE
  return (unsigned short)(r >> 16);
}
__device__ __forceinline__ float bf2f(unsigned short h) {
  union { unsigned u; float f; } v; v.u = ((unsigned)h) << 16;
  return v.f;
}
__device__ __forceinline__ f32x4 mfma16(bf16x8 a, bf16x8 b, f32x4 c) {
  return __builtin_amdgcn_mfma_f32_16x16x32_bf16(a, b, c, 0, 0, 0);
}
__device__ __forceinline__ bf16x8 pack8(const float* __restrict__ p) {
  float4 a = *(const float4*)p;
  float4 b = *(const float4*)(p + 4);
  bf16x8 r;
  r[0] = (short)f2bf(a.x); r[1] = (short)f2bf(a.y);
  r[2] = (short)f2bf(a.z); r[3] = (short)f2bf(a.w);
  r[4] = (short)f2bf(b.x); r[5] = (short)f2bf(b.y);
  r[6] = (short)f2bf(b.z); r[7] = (short)f2bf(b.w);
  return r;
}
// fragment-tiled offset: element (lr = B-col within 16-tile, k) -> tiled index
__device__ __forceinline__ int fragoff(int lr, int k) {
  return (k >> 5) * 512 + ((k >> 3) & 3) * 128 + lr * 8 + (k & 7);
}

// GEMM micro-tile: 4m x 4n, 16 outputs/thread, all-float4 loads.
// acc[mi][ni] += sum_k A[m0+mi][k] * B[k][n0+ni].  (A0 = A row m0; B0 = B + n0)
__device__ __forceinline__ void gemm44(const float* __restrict__ A0, int lda,
                                       const float* __restrict__ B0, int ldb,
                                       int K, float (&acc)[4][4]) {
  for (int k = 0; k < K; k += 4) {
    float a_[4][4], b_[4][4];
#pragma unroll
    for (int mi = 0; mi < 4; ++mi) {
      float4 t = *(const float4*)(A0 + mi * lda + k);
      a_[mi][0] = t.x; a_[mi][1] = t.y; a_[mi][2] = t.z; a_[mi][3] = t.w;
    }
#pragma unroll
    for (int kk = 0; kk < 4; ++kk) {
      float4 t = *(const float4*)(B0 + (size_t)(k + kk) * ldb);
      b_[kk][0] = t.x; b_[kk][1] = t.y; b_[kk][2] = t.z; b_[kk][3] = t.w;
    }
#pragma unroll
    for (int mi = 0; mi < 4; ++mi)
#pragma unroll
      for (int kk = 0; kk < 4; ++kk)
#pragma unroll
        for (int ni = 0; ni < 4; ++ni)
          acc[mi][ni] += a_[mi][kk] * b_[kk][ni];
  }
}

// ---------------------------------------------------------------------------
// prep1: F->FT ; P = W1@Wo ; Kn_h = Wk_h@Wn_k ; Ke_h = Wk_h@We_k ;
//        WnvT/WevT/W2bT tiled bf16 casts.  Blocks: [0,16)F [16,48)P [48,80)Kn
//        [80,96)Ke [96,224)Wnv [224,288)Wev [288,320)W2.
// ---------------------------------------------------------------------------
__global__ void prep1(const float* __restrict__ Wn, const float* __restrict__ We,
                      const float* __restrict__ Wi, const float* __restrict__ Wo,
                      const float* __restrict__ W1, const float* __restrict__ W2,
                      float* __restrict__ FT, float* __restrict__ P,
                      float* __restrict__ Kn, float* __restrict__ Ke,
                      unsigned short* __restrict__ WnvT, unsigned short* __restrict__ WevT,
                      unsigned short* __restrict__ W2bT) {
  const int bid = blockIdx.x, tid = threadIdx.x;
  const int tm = tid >> 5, tn = tid & 31;   // 8 x 32 thread tile
  if (bid < 16) {                           // F [512 m, 128 n] K=512 -> FT[n][m]
    int m = bid * 32 + tm * 4, n0 = tn * 4;
    float acc[4][4] = {};
    gemm44(Wi + m * 512, 512, We + n0, 128, 512, acc);
#pragma unroll
    for (int mi = 0; mi < 4; ++mi)
#pragma unroll
      for (int ni = 0; ni < 4; ++ni) FT[(n0 + ni) * 512 + m + mi] = acc[mi][ni];
  } else if (bid < 48) {                    // P [256 m, 512 n] K=512
    int b = bid - 16; int m = (b >> 2) * 32 + tm * 4, n0 = (b & 3) * 128 + tn * 4;
    float acc[4][4] = {};
    gemm44(W1 + m * 512, 512, Wo + n0, 512, 512, acc);
#pragma unroll
    for (int mi = 0; mi < 4; ++mi)
#pragma unroll
      for (int ni = 0; ni < 4; ++ni) P[(m + mi) * 512 + n0 + ni] = acc[mi][ni];
  } else if (bid < 80) {                    // Kn_h [256 c, 256 b] K=512
    int b = bid - 48; int h = b >> 4, r = b & 15;
    int c = (r >> 1) * 32 + tm * 4, b0 = (r & 1) * 128 + tn * 4;
    float acc[4][4] = {};
    gemm44(Wi + (size_t)(512 + h * 256 + c) * 512, 512, Wn + 512 * 256 + b0, 256, 512, acc);
#pragma unroll
    for (int mi = 0; mi < 4; ++mi)
#pragma unroll
      for (int ni = 0; ni < 4; ++ni) Kn[h * 65536 + (c + mi) * 256 + b0 + ni] = acc[mi][ni];
  } else if (bid < 96) {                    // Ke_h [256 c, 128 b] K=512
    int b = bid - 80; int h = b >> 3, r = b & 7;
    int c = r * 32 + tm * 4, b0 = tn * 4;
    float acc[4][4] = {};
    gemm44(Wi + (size_t)(512 + h * 256 + c) * 512, 512, We + 512 * 128 + b0, 128, 512, acc);
#pragma unroll
    for (int mi = 0; mi < 4; ++mi)
#pragma unroll
      for (int ni = 0; ni < 4; ++ni) Ke[h * 32768 + (c + mi) * 128 + b0 + ni] = acc[mi][ni];
  } else if (bid < 224) {                   // Wn_v -> bf16 TILED
    int i = ((bid - 96) * 256 + tid) * 4;
#pragma unroll
    for (int t = 0; t < 4; ++t) {
      int ii = i + t; int vrow = ii >> 8, k = ii & 255;
      WnvT[(vrow >> 4) * 4096 + fragoff(vrow & 15, k)] = f2bf(Wn[262144 + ii]);
    }
  } else if (bid < 288) {                   // We_v -> bf16 TILED
    int i = ((bid - 224) * 256 + tid) * 4;
#pragma unroll
    for (int t = 0; t < 4; ++t) {
      int ii = i + t; int vrow = ii >> 7, k = ii & 127;
      WevT[(vrow >> 4) * 2048 + fragoff(vrow & 15, k)] = f2bf(We[131072 + ii]);
    }
  } else {                                  // W2 -> bf16 TILED
    int i = ((bid - 288) * 256 + tid) * 4;
#pragma unroll
    for (int t = 0; t < 4; ++t) {
      int ii = i + t; int o = ii >> 8, k = ii & 255;
      W2bT[(k >> 6) * 8192 + ((k >> 5) & 1) * 4096 + (o >> 4) * 512 + fragoff(o & 15, k & 31)] =
          f2bf(W2[ii]);
    }
  }
}

// ---------------------------------------------------------------------------
// prep2: MtnT = F_h^T@Kn_h ; MteT = F_h^T@Ke_h ; QmT_h = P_h@Wv_h ; c2.
//        Blocks: [0,16)Mtn [16,24)Mte [24,88)Qm [88]c2.
// ---------------------------------------------------------------------------
__global__ void prep2(const float* __restrict__ Wi, const float* __restrict__ W1,
                      const float* __restrict__ bi, const float* __restrict__ bo,
                      const float* __restrict__ b1,
                      const float* __restrict__ FT, const float* __restrict__ P,
                      const float* __restrict__ Kn, const float* __restrict__ Ke,
                      unsigned short* __restrict__ MtnT, unsigned short* __restrict__ MteT,
                      unsigned short* __restrict__ QmT, float* __restrict__ c2) {
  const int bid = blockIdx.x, tid = threadIdx.x;
  const int tm = tid >> 5, tn = tid & 31;
  if (bid < 16) {                           // Mtn_h [128 a, 256 b] K=256
    int h = bid >> 3, r = bid & 7;
    int a = (r >> 1) * 32 + tm * 4, b0 = (r & 1) * 128 + tn * 4;
    float acc[4][4] = {};
    gemm44(FT + a * 512 + h * 256, 512, Kn + h * 65536 + b0, 256, 256, acc);
#pragma unroll
    for (int mi = 0; mi < 4; ++mi)
#pragma unroll
      for (int ni = 0; ni < 4; ++ni) {
        int aa = a + mi, bb = b0 + ni;
        MtnT[(h * 2 + (bb >> 7)) * 16384 + ((bb >> 5) & 3) * 4096 + ((bb >> 4) & 1) * 2048 +
             fragoff(bb & 15, aa)] = f2bf(acc[mi][ni]);
      }
  } else if (bid < 24) {                    // Mte_h [128 a, 128 b] K=256
    int b = bid - 16; int h = b >> 2, r = b & 3;
    int a = r * 32 + tm * 4, b0 = tn * 4;
    float acc[4][4] = {};
    gemm44(FT + a * 512 + h * 256, 512, Ke + h * 32768 + b0, 128, 256, acc);
#pragma unroll
    for (int mi = 0; mi < 4; ++mi)
#pragma unroll
      for (int ni = 0; ni < 4; ++ni) {
        int aa = a + mi, bb = b0 + ni;
        MteT[h * 16384 + ((bb >> 5) & 3) * 4096 + ((bb >> 4) & 1) * 2048 +
             fragoff(bb & 15, aa)] = f2bf(acc[mi][ni]);
      }
  } else if (bid < 88) {                    // Qm_h [256 i, 512 t] K=256
    int b = bid - 24; int h = b >> 5, r = b & 31;
    int i = (r >> 2) * 32 + tm * 4, t0 = (r & 3) * 128 + tn * 4;
    float acc[4][4] = {};
    gemm44(P + i * 512 + h * 256, 512, Wi + (size_t)(1024 + h * 256) * 512 + t0, 512, 256, acc);
#pragma unroll
    for (int mi = 0; mi < 4; ++mi)
#pragma unroll
      for (int ni = 0; ni < 4; ++ni) {
        int ii = i + mi, tt = t0 + ni;
        QmT[(tt >> 5) * 16384 + h * 8192 + (ii >> 4) * 512 + fragoff(ii & 15, tt & 31)] =
            f2bf(acc[mi][ni]);
      }
  } else {                                  // c2: b1 + P@bv + W1@bo (one block)
    float cc = b1[tid];
    for (int c = 0; c < 512; ++c) cc += P[tid * 512 + c] * bi[1024 + c] + W1[tid * 512 + c] * bo[c];
    c2[tid] = cc;
  }
}

// ---------------------------------------------------------------------------
// Fused kernel helpers (R5/R8 VERBATIM from here down)
// ---------------------------------------------------------------------------
__device__ __forceinline__ void stage32k(unsigned short* lds, const unsigned short* __restrict__ src,
                                         int tid) {
#pragma unroll
  for (int i = 0; i < 8; ++i) {
    int seg = i * 256 + tid;
    *(int4*)(lds + seg * 8) = *(const int4*)(src + seg * 8);
  }
}

template <int AOFS>
__device__ __forceinline__ void p1n(const unsigned short* __restrict__ srcT,
                                    unsigned short* sflat, unsigned short (&tb)[16][40],
                                    const bf16x8 (&au)[8], const bf16x8 (&av)[8],
                                    const bf16x8 (&ae)[4], int tid, int lrow, int lgrp,
                                    float& su, float& sv) {
  stage32k(sflat, srcT, tid);
  __syncthreads();
  const int lane8 = (lgrp * 16 + lrow) * 8;
#pragma unroll
  for (int c = 0; c < 4; ++c) {
    f32x4 acc0 = {0.f, 0.f, 0.f, 0.f}, acc1 = {0.f, 0.f, 0.f, 0.f};
#pragma unroll
    for (int kt = 0; kt < 4; ++kt) {
      bf16x8 b0 = *(bf16x8*)(sflat + c * 4096 + kt * 512 + lane8);
      bf16x8 b1f = *(bf16x8*)(sflat + c * 4096 + 2048 + kt * 512 + lane8);
      acc0 = mfma16(ae[kt], b0, acc0);
      acc1 = mfma16(ae[kt], b1f, acc1);
    }
#pragma unroll
    for (int j = 0; j < 4; ++j) {
      tb[lgrp * 4 + j][lrow] = f2bf(acc0[j]);
      tb[lgrp * 4 + j][16 + lrow] = f2bf(acc1[j]);
    }
    bf16x8 y = *(bf16x8*)&tb[lrow][lgrp * 8];
#pragma unroll
    for (int j = 0; j < 8; ++j) {
      float yf = bf2f((unsigned short)y[j]);
      su += yf * bf2f((unsigned short)au[AOFS + c][j]);
      sv += yf * bf2f((unsigned short)av[AOFS + c][j]);
    }
  }
  __syncthreads();
}

__device__ __forceinline__ void p1e(const unsigned short* __restrict__ srcT,
                                    unsigned short* sflat, unsigned short (&tb)[16][40],
                                    const bf16x8 (&ae)[4], int tid, int lrow, int lgrp,
                                    float& se) {
  stage32k(sflat, srcT, tid);
  __syncthreads();
  const int lane8 = (lgrp * 16 + lrow) * 8;
#pragma unroll
  for (int c = 0; c < 4; ++c) {
    f32x4 acc0 = {0.f, 0.f, 0.f, 0.f}, acc1 = {0.f, 0.f, 0.f, 0.f};
#pragma unroll
    for (int kt = 0; kt < 4; ++kt) {
      bf16x8 b0 = *(bf16x8*)(sflat + c * 4096 + kt * 512 + lane8);
      bf16x8 b1f = *(bf16x8*)(sflat + c * 4096 + 2048 + kt * 512 + lane8);
      acc0 = mfma16(ae[kt], b0, acc0);
      acc1 = mfma16(ae[kt], b1f, acc1);
    }
#pragma unroll
    for (int j = 0; j < 4; ++j) {
      tb[lgrp * 4 + j][lrow] = f2bf(acc0[j]);
      tb[lgrp * 4 + j][16 + lrow] = f2bf(acc1[j]);
    }
    bf16x8 y = *(bf16x8*)&tb[lrow][lgrp * 8];
#pragma unroll
    for (int j = 0; j < 8; ++j)
      se += bf2f((unsigned short)y[j]) * bf2f((unsigned short)ae[c][j]);
  }
  __syncthreads();
}

// ---------------------------------------------------------------------------
// Fused main kernel: 512 blocks x 256 threads (4 waves x 16 rows). R8 VERBATIM.
// ---------------------------------------------------------------------------
__global__ __launch_bounds__(TPB, 1) void fused_kernel(
    const float* __restrict__ Xu, const float* __restrict__ Xv, const float* __restrict__ Xe,
    const float* __restrict__ bn, const float* __restrict__ be, const float* __restrict__ b2,
    const unsigned short* __restrict__ MtnT, const unsigned short* __restrict__ MteT,
    const unsigned short* __restrict__ WnvT, const unsigned short* __restrict__ WevT,
    const unsigned short* __restrict__ QmT, const unsigned short* __restrict__ W2bT,
    const float* __restrict__ c2, float* __restrict__ Out) {
  // buf b at sStage + b*14336: Wnv[0,4096) Wev[4096,6144) Qm-half[6144,14336)
  __shared__ unsigned short sStage[28672];          // 56 KB
  __shared__ unsigned short sTbuf[4][2][16][40];    // 10 KB wave-local bounce
  __shared__ float sAttn[4][16][8];                 // 2 KB

  const int tid = threadIdx.x;
  const int wave = tid >> 6;
  const int lane = tid & 63;
  const int lrow = lane & 15, lgrp = lane >> 4;
  const int lane8 = lane * 8;
  const int r0 = blockIdx.x * 64 + wave * 16;

  // ---- A fragments (rows of this wave), fp32 -> bf16 ----
  bf16x8 au[8], av[8], ae[4];
  {
    const float* xu = Xu + (size_t)(r0 + lrow) * 256;
    const float* xv = Xv + (size_t)(r0 + lrow) * 256;
    const float* xe = Xe + (size_t)(r0 + lrow) * 128;
#pragma unroll
    for (int kt = 0; kt < 8; ++kt) {
      int off = kt * 32 + lgrp * 8;
      au[kt] = pack8(xu + off);
      av[kt] = pack8(xv + off);
    }
#pragma unroll
    for (int kt = 0; kt < 4; ++kt) ae[kt] = pack8(xe + kt * 32 + lgrp * 8);
  }

  // ================= Phase 1: scores (6 staged 32KB slices) =================
  float su0 = 0.f, sv0 = 0.f, se0 = 0.f, su1 = 0.f, sv1 = 0.f, se1 = 0.f;
  p1n<0>(MtnT,          sStage, sTbuf[wave][0], au, av, ae, tid, lrow, lgrp, su0, sv0);
  p1n<4>(MtnT + 16384,  sStage, sTbuf[wave][0], au, av, ae, tid, lrow, lgrp, su0, sv0);
  p1n<0>(MtnT + 32768,  sStage, sTbuf[wave][0], au, av, ae, tid, lrow, lgrp, su1, sv1);
  p1n<4>(MtnT + 49152,  sStage, sTbuf[wave][0], au, av, ae, tid, lrow, lgrp, su1, sv1);
  p1e(MteT,          sStage, sTbuf[wave][0], ae, tid, lrow, lgrp, se0);
  p1e(MteT + 16384,  sStage, sTbuf[wave][0], ae, tid, lrow, lgrp, se1);

  su0 += __shfl_xor(su0, 16); su0 += __shfl_xor(su0, 32);
  sv0 += __shfl_xor(sv0, 16); sv0 += __shfl_xor(sv0, 32);
  se0 += __shfl_xor(se0, 16); se0 += __shfl_xor(se0, 32);
  su1 += __shfl_xor(su1, 16); su1 += __shfl_xor(su1, 32);
  sv1 += __shfl_xor(sv1, 16); sv1 += __shfl_xor(sv1, 32);
  se1 += __shfl_xor(se1, 16); se1 += __shfl_xor(se1, 32);
  if (lane < 16) {
    sAttn[wave][lrow][0] = su0; sAttn[wave][lrow][1] = sv0; sAttn[wave][lrow][2] = se0;
    sAttn[wave][lrow][3] = su1; sAttn[wave][lrow][4] = sv1; sAttn[wave][lrow][5] = se1;
  }
  // softmax over s (scale 1/16); wave-local
  if (lane < 16) {
#pragma unroll
    for (int h = 0; h < 2; ++h) {
      float s0 = sAttn[wave][lrow][h * 3 + 0] * 0.0625f;
      float s1 = sAttn[wave][lrow][h * 3 + 1] * 0.0625f;
      float s2 = sAttn[wave][lrow][h * 3 + 2] * 0.0625f;
      float m = fmaxf(s0, fmaxf(s1, s2));
      float e0 = __expf(s0 - m), e1 = __expf(s1 - m), e2 = __expf(s2 - m);
      float inv = 1.f / (e0 + e1 + e2);
      sAttn[wave][lrow][h * 3 + 0] = e0 * inv;
      sAttn[wave][lrow][h * 3 + 1] = e1 * inv;
      sAttn[wave][lrow][h * 3 + 2] = e2 * inv;
    }
  }

  // ================= Phase 2: v-GEMM + vbar + Q-GEMM, 32 staged chunks ======
  f32x4 h1acc[16];
#pragma unroll
  for (int i = 0; i < 16; ++i) h1acc[i] = (f32x4){0.f, 0.f, 0.f, 0.f};

  // prologue: buf0 = {Wnv(0), Wev(0), Qm pair0 half1}
  {
#pragma unroll
    for (int i = 0; i < 7; ++i) {
      int seg = i * 256 + tid;
      int4 v;
      if (i < 2)       v = *(const int4*)(WnvT + seg * 8);
      else if (i == 2) v = *(const int4*)(WevT + (seg - 512) * 8);
      else             v = *(const int4*)(QmT + 8192 + (seg - 768) * 8);
      *(int4*)(sStage + seg * 8) = v;
    }
  }
  __syncthreads();

#pragma unroll 2
  for (int t = 0; t < 32; ++t) {
    const int cur = t & 1;
    unsigned short* wb = sStage + cur * 14336;
    unsigned short* nb = sStage + (cur ^ 1) * 14336;

    // T14: issue prefetch loads for chunk t+1 (clamped at the end, harmless dup)
    const int cn = (t < 31) ? (t + 1) : 31;
    int qp = cur ? ((t + 1) >> 1) : (t >> 1);
    if (qp > 15) qp = 15;
    const int qoff = qp * 16384 + cur * 8192;
    int4 st0 = *(const int4*)(WnvT + cn * 4096 + tid * 8);
    int4 st1 = *(const int4*)(WnvT + cn * 4096 + (256 + tid) * 8);
    int4 st2 = *(const int4*)(WevT + cn * 2048 + tid * 8);
    int4 st3 = *(const int4*)(QmT + qoff + tid * 8);
    int4 st4 = *(const int4*)(QmT + qoff + (256 + tid) * 8);
    int4 st5 = *(const int4*)(QmT + qoff + (512 + tid) * 8);
    int4 st6 = *(const int4*)(QmT + qoff + (768 + tid) * 8);

    // v-GEMM for this chunk's 16 v-cols
    f32x4 vu = {0.f, 0.f, 0.f, 0.f}, vv = {0.f, 0.f, 0.f, 0.f}, ve = {0.f, 0.f, 0.f, 0.f};
#pragma unroll
    for (int kt = 0; kt < 8; ++kt) {
      bf16x8 b = *(bf16x8*)(wb + kt * 512 + lane8);
      vu = mfma16(au[kt], b, vu);
      vv = mfma16(av[kt], b, vv);
    }
#pragma unroll
    for (int kt = 0; kt < 4; ++kt) {
      bf16x8 b = *(bf16x8*)(wb + 4096 + kt * 512 + lane8);
      ve = mfma16(ae[kt], b, ve);
    }
    const int vrow = t * 16 + lrow;
    const float bnv = bn[1024 + vrow], bev = be[1024 + vrow];
#pragma unroll
    for (int j = 0; j < 4; ++j) {
      const float* ar = &sAttn[wave][lgrp * 4 + j][0];
#pragma unroll
      for (int h = 0; h < 2; ++h) {
        float a0 = ar[h * 3 + 0], a1 = ar[h * 3 + 1], a2 = ar[h * 3 + 2];
        float vb = a0 * vu[j] + a1 * vv[j] + a2 * ve[j] + (a0 + a1) * bnv + a2 * bev;
        sTbuf[wave][h][lgrp * 4 + j][cur * 16 + lrow] = f2bf(vb);
      }
    }

    if (cur) {  // odd chunk: Q-GEMM over the completed 32-col pair
#pragma unroll
      for (int h2 = 0; h2 < 2; ++h2) {
        const unsigned short* qb = (h2 == 0 ? wb : nb) + 6144;
        bf16x8 vbx = *(bf16x8*)&sTbuf[wave][h2][lrow][lgrp * 8];
#pragma unroll
        for (int nt = 0; nt < 16; ++nt) {
          bf16x8 bq = *(bf16x8*)(qb + nt * 512 + lane8);
          h1acc[nt] = mfma16(vbx, bq, h1acc[nt]);
        }
      }
      __syncthreads();  // all waves done reading nb's Qm slot before overwrite
    }

    // write prefetched chunk t+1 into the other buffer
    *(int4*)(nb + tid * 8) = st0;
    *(int4*)(nb + (256 + tid) * 8) = st1;
    *(int4*)(nb + (512 + tid) * 8) = st2;
    *(int4*)(nb + (768 + tid) * 8) = st3;
    *(int4*)(nb + (1024 + tid) * 8) = st4;
    *(int4*)(nb + (1280 + tid) * 8) = st5;
    *(int4*)(nb + (1536 + tid) * 8) = st6;
    __syncthreads();
  }

  // ================= Phase 3: silu + W2 (2 staged 32KB halves) ==============
  f32x4 outacc[8];
#pragma unroll
  for (int i = 0; i < 8; ++i) outacc[i] = (f32x4){0.f, 0.f, 0.f, 0.f};

#pragma unroll
  for (int hh = 0; hh < 2; ++hh) {
    if (hh) __syncthreads();  // protect previous half's reads
    stage32k(sStage, W2bT + hh * 16384, tid);
    __syncthreads();
#pragma unroll
    for (int kc = 0; kc < 2; ++kc) {
      const int kg = hh * 2 + kc;
#pragma unroll
      for (int tt = 0; tt < 4; ++tt) {
        int nt = kg * 4 + tt;
        float c2v = c2[nt * 16 + lrow];
#pragma unroll
        for (int j = 0; j < 4; ++j) {
          float x = h1acc[nt][j] + c2v;
          float s = x / (1.f + __expf(-x));  // silu
          sTbuf[wave][tt >> 1][lgrp * 4 + j][(tt & 1) * 16 + lrow] = f2bf(s);
        }
      }
#pragma unroll
      for (int p = 0; p < 2; ++p) {
        bf16x8 hA = *(bf16x8*)&sTbuf[wave][p][lrow][lgrp * 8];
#pragma unroll
        for (int ot = 0; ot < 8; ++ot) {
          bf16x8 w2 = *(bf16x8*)(sStage + kc * 8192 + p * 4096 + ot * 512 + lane8);
          outacc[ot] = mfma16(hA, w2, outacc[ot]);
        }
      }
    }
  }

  // epilogue: out = outacc + b2 (fp32)
#pragma unroll
  for (int ot = 0; ot < 8; ++ot) {
    int col = ot * 16 + lrow;
    float b2v = b2[col];
#pragma unroll
    for (int j = 0; j < 4; ++j)
      Out[(size_t)(r0 + lgrp * 4 + j) * 128 + col] = outacc[ot][j] + b2v;
  }
}

// ---------------------------------------------------------------------------
extern "C" void kernel_launch(void* const* d_in, const int* in_sizes, int n_in,
                              void* d_out, int out_size, void* d_ws, size_t ws_size,
                              hipStream_t stream) {
  const float* Xu = (const float*)d_in[0];
  const float* Xv = (const float*)d_in[1];
  const float* Xe = (const float*)d_in[2];
  const float* Wn = (const float*)d_in[3];
  const float* bn = (const float*)d_in[4];
  const float* We = (const float*)d_in[5];
  const float* be = (const float*)d_in[6];
  const float* Wi = (const float*)d_in[7];
  const float* bi = (const float*)d_in[8];
  const float* Wo = (const float*)d_in[9];
  const float* bo = (const float*)d_in[10];
  const float* W1 = (const float*)d_in[11];
  const float* b1 = (const float*)d_in[12];
  const float* W2 = (const float*)d_in[13];
  const float* b2 = (const float*)d_in[14];

  // ws layout, NO aliasing; total EXACTLY 2,753,536 B (= R5/R8-proven ceiling).
  char* ws = (char*)d_ws;
  float* FT = (float*)(ws + 0);                            // [128,512] f32   262144 B
  float* P  = (float*)(ws + 262144);                       // [256,512] f32   524288 B
  float* Kn = (float*)(ws + 786432);                       // [2][256,256]    524288 B
  float* Ke = (float*)(ws + 1310720);                      // [2][256,128]    262144 B
  unsigned short* QmT  = (unsigned short*)(ws + 1572864);  // 262144 bf16     524288 B
  unsigned short* WnvT = (unsigned short*)(ws + 2097152);  // 131072 bf16     262144 B
  unsigned short* WevT = (unsigned short*)(ws + 2359296);  // 65536 bf16      131072 B
  unsigned short* MtnT = (unsigned short*)(ws + 2490368);  // 65536 bf16      131072 B
  unsigned short* MteT = (unsigned short*)(ws + 2621440);  // 32768 bf16       65536 B
  unsigned short* W2bT = (unsigned short*)(ws + 2686976);  // 32768 bf16       65536 B
  float* c2 = (float*)(ws + 2752512);                      // [256] f32         1024 B

  prep1<<<320, 256, 0, stream>>>(Wn, We, Wi, Wo, W1, W2, FT, P, Kn, Ke, WnvT, WevT, W2bT);
  prep2<<<89, 256, 0, stream>>>(Wi, W1, bi, bo, b1, FT, P, Kn, Ke, MtnT, MteT, QmT, c2);
  fused_kernel<<<512, 256, 0, stream>>>(Xu, Xv, Xe, bn, be, b2, MtnT, MteT, WnvT, WevT, QmT, W2bT,
                                        c2, (float*)d_out);
}

// Round 10
// 186.819 us; speedup vs baseline: 1.3056x; 1.1483x over previous
//
#include <hip/hip_runtime.h>

// MiniAttentionLayer fused kernel for MI355X (gfx950).
//
// ROUND 10: single-variable occupancy fix. R9's fused kernel: VGPR_Count 208
// + ~64 AGPR acc = 272 unified regs > 256 => 1 wave/SIMD (12.5% occupancy cap,
// measured 11.4%) => every load/barrier latency fully exposed (~136 cyc/instr
// since R3). FIX: __launch_bounds__(256,2) caps unified regs at 256/wave,
// doubling occupancy to 2 waves/SIMD. Everything else is R9 VERBATIM.
// Falsifier: WRITE_SIZE >> 16MB means the allocator spilled instead of shaved.
//
//   score[h,s]*16 = x_e^T M_{h,s} x_s ; softmax -> attn
//   M^n_h = F_h^T @ (Wk_h @ Wn_k) ; M^e_h = F_h^T @ (Wk_h @ We_k) ; F = Wq@We_q
//   vbar_h = sum_s attn[h,s] v_s ; v_s = W*_v x_s (+ b*_v)
//   h1pre = Qm @ [vbar_0|vbar_1] + c2 ; Qm_h = P @ Wv_h ; P = W1@Wo
//   out = W2 @ silu(h1pre) + b2

#define TPB 256

typedef __attribute__((ext_vector_type(8))) short bf16x8;
typedef __attribute__((ext_vector_type(4))) float f32x4;

__device__ __forceinline__ unsigned short f2bf(float f) {
  union { float f; unsigned u; } v; v.f = f;
  unsigned r = v.u + 0x7FFFu + ((v.u >> 16) & 1u);  // RNE
  return (unsigned short)(r >> 16);
}
__device__ __forceinline__ float bf2f(unsigned short h) {
  union { unsigned u; float f; } v; v.u = ((unsigned)h) << 16;
  return v.f;
}
__device__ __forceinline__ f32x4 mfma16(bf16x8 a, bf16x8 b, f32x4 c) {
  return __builtin_amdgcn_mfma_f32_16x16x32_bf16(a, b, c, 0, 0, 0);
}
__device__ __forceinline__ bf16x8 pack8(const float* __restrict__ p) {
  float4 a = *(const float4*)p;
  float4 b = *(const float4*)(p + 4);
  bf16x8 r;
  r[0] = (short)f2bf(a.x); r[1] = (short)f2bf(a.y);
  r[2] = (short)f2bf(a.z); r[3] = (short)f2bf(a.w);
  r[4] = (short)f2bf(b.x); r[5] = (short)f2bf(b.y);
  r[6] = (short)f2bf(b.z); r[7] = (short)f2bf(b.w);
  return r;
}
// fragment-tiled offset: element (lr = B-col within 16-tile, k) -> tiled index
__device__ __forceinline__ int fragoff(int lr, int k) {
  return (k >> 5) * 512 + ((k >> 3) & 3) * 128 + lr * 8 + (k & 7);
}

// GEMM micro-tile: 4m x 4n, 16 outputs/thread, all-float4 loads.
// acc[mi][ni] += sum_k A[m0+mi][k] * B[k][n0+ni].  (A0 = A row m0; B0 = B + n0)
__device__ __forceinline__ void gemm44(const float* __restrict__ A0, int lda,
                                       const float* __restrict__ B0, int ldb,
                                       int K, float (&acc)[4][4]) {
  for (int k = 0; k < K; k += 4) {
    float a_[4][4], b_[4][4];
#pragma unroll
    for (int mi = 0; mi < 4; ++mi) {
      float4 t = *(const float4*)(A0 + mi * lda + k);
      a_[mi][0] = t.x; a_[mi][1] = t.y; a_[mi][2] = t.z; a_[mi][3] = t.w;
    }
#pragma unroll
    for (int kk = 0; kk < 4; ++kk) {
      float4 t = *(const float4*)(B0 + (size_t)(k + kk) * ldb);
      b_[kk][0] = t.x; b_[kk][1] = t.y; b_[kk][2] = t.z; b_[kk][3] = t.w;
    }
#pragma unroll
    for (int mi = 0; mi < 4; ++mi)
#pragma unroll
      for (int kk = 0; kk < 4; ++kk)
#pragma unroll
        for (int ni = 0; ni < 4; ++ni)
          acc[mi][ni] += a_[mi][kk] * b_[kk][ni];
  }
}

// ---------------------------------------------------------------------------
// prep1: F->FT ; P = W1@Wo ; Kn_h = Wk_h@Wn_k ; Ke_h = Wk_h@We_k ;
//        WnvT/WevT/W2bT tiled bf16 casts.
// ---------------------------------------------------------------------------
__global__ void prep1(const float* __restrict__ Wn, const float* __restrict__ We,
                      const float* __restrict__ Wi, const float* __restrict__ Wo,
                      const float* __restrict__ W1, const float* __restrict__ W2,
                      float* __restrict__ FT, float* __restrict__ P,
                      float* __restrict__ Kn, float* __restrict__ Ke,
                      unsigned short* __restrict__ WnvT, unsigned short* __restrict__ WevT,
                      unsigned short* __restrict__ W2bT) {
  const int bid = blockIdx.x, tid = threadIdx.x;
  const int tm = tid >> 5, tn = tid & 31;   // 8 x 32 thread tile
  if (bid < 16) {                           // F [512 m, 128 n] K=512 -> FT[n][m]
    int m = bid * 32 + tm * 4, n0 = tn * 4;
    float acc[4][4] = {};
    gemm44(Wi + m * 512, 512, We + n0, 128, 512, acc);
#pragma unroll
    for (int mi = 0; mi < 4; ++mi)
#pragma unroll
      for (int ni = 0; ni < 4; ++ni) FT[(n0 + ni) * 512 + m + mi] = acc[mi][ni];
  } else if (bid < 48) {                    // P [256 m, 512 n] K=512
    int b = bid - 16; int m = (b >> 2) * 32 + tm * 4, n0 = (b & 3) * 128 + tn * 4;
    float acc[4][4] = {};
    gemm44(W1 + m * 512, 512, Wo + n0, 512, 512, acc);
#pragma unroll
    for (int mi = 0; mi < 4; ++mi)
#pragma unroll
      for (int ni = 0; ni < 4; ++ni) P[(m + mi) * 512 + n0 + ni] = acc[mi][ni];
  } else if (bid < 80) {                    // Kn_h [256 c, 256 b] K=512
    int b = bid - 48; int h = b >> 4, r = b & 15;
    int c = (r >> 1) * 32 + tm * 4, b0 = (r & 1) * 128 + tn * 4;
    float acc[4][4] = {};
    gemm44(Wi + (size_t)(512 + h * 256 + c) * 512, 512, Wn + 512 * 256 + b0, 256, 512, acc);
#pragma unroll
    for (int mi = 0; mi < 4; ++mi)
#pragma unroll
      for (int ni = 0; ni < 4; ++ni) Kn[h * 65536 + (c + mi) * 256 + b0 + ni] = acc[mi][ni];
  } else if (bid < 96) {                    // Ke_h [256 c, 128 b] K=512
    int b = bid - 80; int h = b >> 3, r = b & 7;
    int c = r * 32 + tm * 4, b0 = tn * 4;
    float acc[4][4] = {};
    gemm44(Wi + (size_t)(512 + h * 256 + c) * 512, 512, We + 512 * 128 + b0, 128, 512, acc);
#pragma unroll
    for (int mi = 0; mi < 4; ++mi)
#pragma unroll
      for (int ni = 0; ni < 4; ++ni) Ke[h * 32768 + (c + mi) * 128 + b0 + ni] = acc[mi][ni];
  } else if (bid < 224) {                   // Wn_v -> bf16 TILED
    int i = ((bid - 96) * 256 + tid) * 4;
#pragma unroll
    for (int t = 0; t < 4; ++t) {
      int ii = i + t; int vrow = ii >> 8, k = ii & 255;
      WnvT[(vrow >> 4) * 4096 + fragoff(vrow & 15, k)] = f2bf(Wn[262144 + ii]);
    }
  } else if (bid < 288) {                   // We_v -> bf16 TILED
    int i = ((bid - 224) * 256 + tid) * 4;
#pragma unroll
    for (int t = 0; t < 4; ++t) {
      int ii = i + t; int vrow = ii >> 7, k = ii & 127;
      WevT[(vrow >> 4) * 2048 + fragoff(vrow & 15, k)] = f2bf(We[131072 + ii]);
    }
  } else {                                  // W2 -> bf16 TILED
    int i = ((bid - 288) * 256 + tid) * 4;
#pragma unroll
    for (int t = 0; t < 4; ++t) {
      int ii = i + t; int o = ii >> 8, k = ii & 255;
      W2bT[(k >> 6) * 8192 + ((k >> 5) & 1) * 4096 + (o >> 4) * 512 + fragoff(o & 15, k & 31)] =
          f2bf(W2[ii]);
    }
  }
}

// ---------------------------------------------------------------------------
// prep2: MtnT = F_h^T@Kn_h ; MteT = F_h^T@Ke_h ; QmT_h = P_h@Wv_h ; c2.
// ---------------------------------------------------------------------------
__global__ void prep2(const float* __restrict__ Wi, const float* __restrict__ W1,
                      const float* __restrict__ bi, const float* __restrict__ bo,
                      const float* __restrict__ b1,
                      const float* __restrict__ FT, const float* __restrict__ P,
                      const float* __restrict__ Kn, const float* __restrict__ Ke,
                      unsigned short* __restrict__ MtnT, unsigned short* __restrict__ MteT,
                      unsigned short* __restrict__ QmT, float* __restrict__ c2) {
  const int bid = blockIdx.x, tid = threadIdx.x;
  const int tm = tid >> 5, tn = tid & 31;
  if (bid < 16) {                           // Mtn_h [128 a, 256 b] K=256
    int h = bid >> 3, r = bid & 7;
    int a = (r >> 1) * 32 + tm * 4, b0 = (r & 1) * 128 + tn * 4;
    float acc[4][4] = {};
    gemm44(FT + a * 512 + h * 256, 512, Kn + h * 65536 + b0, 256, 256, acc);
#pragma unroll
    for (int mi = 0; mi < 4; ++mi)
#pragma unroll
      for (int ni = 0; ni < 4; ++ni) {
        int aa = a + mi, bb = b0 + ni;
        MtnT[(h * 2 + (bb >> 7)) * 16384 + ((bb >> 5) & 3) * 4096 + ((bb >> 4) & 1) * 2048 +
             fragoff(bb & 15, aa)] = f2bf(acc[mi][ni]);
      }
  } else if (bid < 24) {                    // Mte_h [128 a, 128 b] K=256
    int b = bid - 16; int h = b >> 2, r = b & 3;
    int a = r * 32 + tm * 4, b0 = tn * 4;
    float acc[4][4] = {};
    gemm44(FT + a * 512 + h * 256, 512, Ke + h * 32768 + b0, 128, 256, acc);
#pragma unroll
    for (int mi = 0; mi < 4; ++mi)
#pragma unroll
      for (int ni = 0; ni < 4; ++ni) {
        int aa = a + mi, bb = b0 + ni;
        MteT[h * 16384 + ((bb >> 5) & 3) * 4096 + ((bb >> 4) & 1) * 2048 +
             fragoff(bb & 15, aa)] = f2bf(acc[mi][ni]);
      }
  } else if (bid < 88) {                    // Qm_h [256 i, 512 t] K=256
    int b = bid - 24; int h = b >> 5, r = b & 31;
    int i = (r >> 2) * 32 + tm * 4, t0 = (r & 3) * 128 + tn * 4;
    float acc[4][4] = {};
    gemm44(P + i * 512 + h * 256, 512, Wi + (size_t)(1024 + h * 256) * 512 + t0, 512, 256, acc);
#pragma unroll
    for (int mi = 0; mi < 4; ++mi)
#pragma unroll
      for (int ni = 0; ni < 4; ++ni) {
        int ii = i + mi, tt = t0 + ni;
        QmT[(tt >> 5) * 16384 + h * 8192 + (ii >> 4) * 512 + fragoff(ii & 15, tt & 31)] =
            f2bf(acc[mi][ni]);
      }
  } else {                                  // c2: b1 + P@bv + W1@bo (one block)
    float cc = b1[tid];
    for (int c = 0; c < 512; ++c) cc += P[tid * 512 + c] * bi[1024 + c] + W1[tid * 512 + c] * bo[c];
    c2[tid] = cc;
  }
}

// ---------------------------------------------------------------------------
// Fused kernel helpers (R5/R8/R9 VERBATIM from here down except launch bounds)
// ---------------------------------------------------------------------------
__device__ __forceinline__ void stage32k(unsigned short* lds, const unsigned short* __restrict__ src,
                                         int tid) {
#pragma unroll
  for (int i = 0; i < 8; ++i) {
    int seg = i * 256 + tid;
    *(int4*)(lds + seg * 8) = *(const int4*)(src + seg * 8);
  }
}

template <int AOFS>
__device__ __forceinline__ void p1n(const unsigned short* __restrict__ srcT,
                                    unsigned short* sflat, unsigned short (&tb)[16][40],
                                    const bf16x8 (&au)[8], const bf16x8 (&av)[8],
                                    const bf16x8 (&ae)[4], int tid, int lrow, int lgrp,
                                    float& su, float& sv) {
  stage32k(sflat, srcT, tid);
  __syncthreads();
  const int lane8 = (lgrp * 16 + lrow) * 8;
#pragma unroll
  for (int c = 0; c < 4; ++c) {
    f32x4 acc0 = {0.f, 0.f, 0.f, 0.f}, acc1 = {0.f, 0.f, 0.f, 0.f};
#pragma unroll
    for (int kt = 0; kt < 4; ++kt) {
      bf16x8 b0 = *(bf16x8*)(sflat + c * 4096 + kt * 512 + lane8);
      bf16x8 b1f = *(bf16x8*)(sflat + c * 4096 + 2048 + kt * 512 + lane8);
      acc0 = mfma16(ae[kt], b0, acc0);
      acc1 = mfma16(ae[kt], b1f, acc1);
    }
#pragma unroll
    for (int j = 0; j < 4; ++j) {
      tb[lgrp * 4 + j][lrow] = f2bf(acc0[j]);
      tb[lgrp * 4 + j][16 + lrow] = f2bf(acc1[j]);
    }
    bf16x8 y = *(bf16x8*)&tb[lrow][lgrp * 8];
#pragma unroll
    for (int j = 0; j < 8; ++j) {
      float yf = bf2f((unsigned short)y[j]);
      su += yf * bf2f((unsigned short)au[AOFS + c][j]);
      sv += yf * bf2f((unsigned short)av[AOFS + c][j]);
    }
  }
  __syncthreads();
}

__device__ __forceinline__ void p1e(const unsigned short* __restrict__ srcT,
                                    unsigned short* sflat, unsigned short (&tb)[16][40],
                                    const bf16x8 (&ae)[4], int tid, int lrow, int lgrp,
                                    float& se) {
  stage32k(sflat, srcT, tid);
  __syncthreads();
  const int lane8 = (lgrp * 16 + lrow) * 8;
#pragma unroll
  for (int c = 0; c < 4; ++c) {
    f32x4 acc0 = {0.f, 0.f, 0.f, 0.f}, acc1 = {0.f, 0.f, 0.f, 0.f};
#pragma unroll
    for (int kt = 0; kt < 4; ++kt) {
      bf16x8 b0 = *(bf16x8*)(sflat + c * 4096 + kt * 512 + lane8);
      bf16x8 b1f = *(bf16x8*)(sflat + c * 4096 + 2048 + kt * 512 + lane8);
      acc0 = mfma16(ae[kt], b0, acc0);
      acc1 = mfma16(ae[kt], b1f, acc1);
    }
#pragma unroll
    for (int j = 0; j < 4; ++j) {
      tb[lgrp * 4 + j][lrow] = f2bf(acc0[j]);
      tb[lgrp * 4 + j][16 + lrow] = f2bf(acc1[j]);
    }
    bf16x8 y = *(bf16x8*)&tb[lrow][lgrp * 8];
#pragma unroll
    for (int j = 0; j < 8; ++j)
      se += bf2f((unsigned short)y[j]) * bf2f((unsigned short)ae[c][j]);
  }
  __syncthreads();
}

// ---------------------------------------------------------------------------
// Fused main kernel: 512 blocks x 256 threads (4 waves x 16 rows).
// __launch_bounds__(256,2): cap unified regs at 256/wave -> 2 waves/SIMD.
// ---------------------------------------------------------------------------
__global__ __launch_bounds__(TPB, 2) void fused_kernel(
    const float* __restrict__ Xu, const float* __restrict__ Xv, const float* __restrict__ Xe,
    const float* __restrict__ bn, const float* __restrict__ be, const float* __restrict__ b2,
    const unsigned short* __restrict__ MtnT, const unsigned short* __restrict__ MteT,
    const unsigned short* __restrict__ WnvT, const unsigned short* __restrict__ WevT,
    const unsigned short* __restrict__ QmT, const unsigned short* __restrict__ W2bT,
    const float* __restrict__ c2, float* __restrict__ Out) {
  // buf b at sStage + b*14336: Wnv[0,4096) Wev[4096,6144) Qm-half[6144,14336)
  __shared__ unsigned short sStage[28672];          // 56 KB
  __shared__ unsigned short sTbuf[4][2][16][40];    // 10 KB wave-local bounce
  __shared__ float sAttn[4][16][8];                 // 2 KB

  const int tid = threadIdx.x;
  const int wave = tid >> 6;
  const int lane = tid & 63;
  const int lrow = lane & 15, lgrp = lane >> 4;
  const int lane8 = lane * 8;
  const int r0 = blockIdx.x * 64 + wave * 16;

  // ---- A fragments (rows of this wave), fp32 -> bf16 ----
  bf16x8 au[8], av[8], ae[4];
  {
    const float* xu = Xu + (size_t)(r0 + lrow) * 256;
    const float* xv = Xv + (size_t)(r0 + lrow) * 256;
    const float* xe = Xe + (size_t)(r0 + lrow) * 128;
#pragma unroll
    for (int kt = 0; kt < 8; ++kt) {
      int off = kt * 32 + lgrp * 8;
      au[kt] = pack8(xu + off);
      av[kt] = pack8(xv + off);
    }
#pragma unroll
    for (int kt = 0; kt < 4; ++kt) ae[kt] = pack8(xe + kt * 32 + lgrp * 8);
  }

  // ================= Phase 1: scores (6 staged 32KB slices) =================
  float su0 = 0.f, sv0 = 0.f, se0 = 0.f, su1 = 0.f, sv1 = 0.f, se1 = 0.f;
  p1n<0>(MtnT,          sStage, sTbuf[wave][0], au, av, ae, tid, lrow, lgrp, su0, sv0);
  p1n<4>(MtnT + 16384,  sStage, sTbuf[wave][0], au, av, ae, tid, lrow, lgrp, su0, sv0);
  p1n<0>(MtnT + 32768,  sStage, sTbuf[wave][0], au, av, ae, tid, lrow, lgrp, su1, sv1);
  p1n<4>(MtnT + 49152,  sStage, sTbuf[wave][0], au, av, ae, tid, lrow, lgrp, su1, sv1);
  p1e(MteT,          sStage, sTbuf[wave][0], ae, tid, lrow, lgrp, se0);
  p1e(MteT + 16384,  sStage, sTbuf[wave][0], ae, tid, lrow, lgrp, se1);

  su0 += __shfl_xor(su0, 16); su0 += __shfl_xor(su0, 32);
  sv0 += __shfl_xor(sv0, 16); sv0 += __shfl_xor(sv0, 32);
  se0 += __shfl_xor(se0, 16); se0 += __shfl_xor(se0, 32);
  su1 += __shfl_xor(su1, 16); su1 += __shfl_xor(su1, 32);
  sv1 += __shfl_xor(sv1, 16); sv1 += __shfl_xor(sv1, 32);
  se1 += __shfl_xor(se1, 16); se1 += __shfl_xor(se1, 32);
  if (lane < 16) {
    sAttn[wave][lrow][0] = su0; sAttn[wave][lrow][1] = sv0; sAttn[wave][lrow][2] = se0;
    sAttn[wave][lrow][3] = su1; sAttn[wave][lrow][4] = sv1; sAttn[wave][lrow][5] = se1;
  }
  // softmax over s (scale 1/16); wave-local
  if (lane < 16) {
#pragma unroll
    for (int h = 0; h < 2; ++h) {
      float s0 = sAttn[wave][lrow][h * 3 + 0] * 0.0625f;
      float s1 = sAttn[wave][lrow][h * 3 + 1] * 0.0625f;
      float s2 = sAttn[wave][lrow][h * 3 + 2] * 0.0625f;
      float m = fmaxf(s0, fmaxf(s1, s2));
      float e0 = __expf(s0 - m), e1 = __expf(s1 - m), e2 = __expf(s2 - m);
      float inv = 1.f / (e0 + e1 + e2);
      sAttn[wave][lrow][h * 3 + 0] = e0 * inv;
      sAttn[wave][lrow][h * 3 + 1] = e1 * inv;
      sAttn[wave][lrow][h * 3 + 2] = e2 * inv;
    }
  }

  // ================= Phase 2: v-GEMM + vbar + Q-GEMM, 32 staged chunks ======
  f32x4 h1acc[16];
#pragma unroll
  for (int i = 0; i < 16; ++i) h1acc[i] = (f32x4){0.f, 0.f, 0.f, 0.f};

  // prologue: buf0 = {Wnv(0), Wev(0), Qm pair0 half1}
  {
#pragma unroll
    for (int i = 0; i < 7; ++i) {
      int seg = i * 256 + tid;
      int4 v;
      if (i < 2)       v = *(const int4*)(WnvT + seg * 8);
      else if (i == 2) v = *(const int4*)(WevT + (seg - 512) * 8);
      else             v = *(const int4*)(QmT + 8192 + (seg - 768) * 8);
      *(int4*)(sStage + seg * 8) = v;
    }
  }
  __syncthreads();

#pragma unroll 2
  for (int t = 0; t < 32; ++t) {
    const int cur = t & 1;
    unsigned short* wb = sStage + cur * 14336;
    unsigned short* nb = sStage + (cur ^ 1) * 14336;

    // T14: issue prefetch loads for chunk t+1 (clamped at the end, harmless dup)
    const int cn = (t < 31) ? (t + 1) : 31;
    int qp = cur ? ((t + 1) >> 1) : (t >> 1);
    if (qp > 15) qp = 15;
    const int qoff = qp * 16384 + cur * 8192;
    int4 st0 = *(const int4*)(WnvT + cn * 4096 + tid * 8);
    int4 st1 = *(const int4*)(WnvT + cn * 4096 + (256 + tid) * 8);
    int4 st2 = *(const int4*)(WevT + cn * 2048 + tid * 8);
    int4 st3 = *(const int4*)(QmT + qoff + tid * 8);
    int4 st4 = *(const int4*)(QmT + qoff + (256 + tid) * 8);
    int4 st5 = *(const int4*)(QmT + qoff + (512 + tid) * 8);
    int4 st6 = *(const int4*)(QmT + qoff + (768 + tid) * 8);

    // v-GEMM for this chunk's 16 v-cols
    f32x4 vu = {0.f, 0.f, 0.f, 0.f}, vv = {0.f, 0.f, 0.f, 0.f}, ve = {0.f, 0.f, 0.f, 0.f};
#pragma unroll
    for (int kt = 0; kt < 8; ++kt) {
      bf16x8 b = *(bf16x8*)(wb + kt * 512 + lane8);
      vu = mfma16(au[kt], b, vu);
      vv = mfma16(av[kt], b, vv);
    }
#pragma unroll
    for (int kt = 0; kt < 4; ++kt) {
      bf16x8 b = *(bf16x8*)(wb + 4096 + kt * 512 + lane8);
      ve = mfma16(ae[kt], b, ve);
    }
    const int vrow = t * 16 + lrow;
    const float bnv = bn[1024 + vrow], bev = be[1024 + vrow];
#pragma unroll
    for (int j = 0; j < 4; ++j) {
      const float* ar = &sAttn[wave][lgrp * 4 + j][0];
#pragma unroll
      for (int h = 0; h < 2; ++h) {
        float a0 = ar[h * 3 + 0], a1 = ar[h * 3 + 1], a2 = ar[h * 3 + 2];
        float vb = a0 * vu[j] + a1 * vv[j] + a2 * ve[j] + (a0 + a1) * bnv + a2 * bev;
        sTbuf[wave][h][lgrp * 4 + j][cur * 16 + lrow] = f2bf(vb);
      }
    }

    if (cur) {  // odd chunk: Q-GEMM over the completed 32-col pair
#pragma unroll
      for (int h2 = 0; h2 < 2; ++h2) {
        const unsigned short* qb = (h2 == 0 ? wb : nb) + 6144;
        bf16x8 vbx = *(bf16x8*)&sTbuf[wave][h2][lrow][lgrp * 8];
#pragma unroll
        for (int nt = 0; nt < 16; ++nt) {
          bf16x8 bq = *(bf16x8*)(qb + nt * 512 + lane8);
          h1acc[nt] = mfma16(vbx, bq, h1acc[nt]);
        }
      }
      __syncthreads();  // all waves done reading nb's Qm slot before overwrite
    }

    // write prefetched chunk t+1 into the other buffer
    *(int4*)(nb + tid * 8) = st0;
    *(int4*)(nb + (256 + tid) * 8) = st1;
    *(int4*)(nb + (512 + tid) * 8) = st2;
    *(int4*)(nb + (768 + tid) * 8) = st3;
    *(int4*)(nb + (1024 + tid) * 8) = st4;
    *(int4*)(nb + (1280 + tid) * 8) = st5;
    *(int4*)(nb + (1536 + tid) * 8) = st6;
    __syncthreads();
  }

  // ================= Phase 3: silu + W2 (2 staged 32KB halves) ==============
  f32x4 outacc[8];
#pragma unroll
  for (int i = 0; i < 8; ++i) outacc[i] = (f32x4){0.f, 0.f, 0.f, 0.f};

#pragma unroll
  for (int hh = 0; hh < 2; ++hh) {
    if (hh) __syncthreads();  // protect previous half's reads
    stage32k(sStage, W2bT + hh * 16384, tid);
    __syncthreads();
#pragma unroll
    for (int kc = 0; kc < 2; ++kc) {
      const int kg = hh * 2 + kc;
#pragma unroll
      for (int tt = 0; tt < 4; ++tt) {
        int nt = kg * 4 + tt;
        float c2v = c2[nt * 16 + lrow];
#pragma unroll
        for (int j = 0; j < 4; ++j) {
          float x = h1acc[nt][j] + c2v;
          float s = x / (1.f + __expf(-x));  // silu
          sTbuf[wave][tt >> 1][lgrp * 4 + j][(tt & 1) * 16 + lrow] = f2bf(s);
        }
      }
#pragma unroll
      for (int p = 0; p < 2; ++p) {
        bf16x8 hA = *(bf16x8*)&sTbuf[wave][p][lrow][lgrp * 8];
#pragma unroll
        for (int ot = 0; ot < 8; ++ot) {
          bf16x8 w2 = *(bf16x8*)(sStage + kc * 8192 + p * 4096 + ot * 512 + lane8);
          outacc[ot] = mfma16(hA, w2, outacc[ot]);
        }
      }
    }
  }

  // epilogue: out = outacc + b2 (fp32)
#pragma unroll
  for (int ot = 0; ot < 8; ++ot) {
    int col = ot * 16 + lrow;
    float b2v = b2[col];
#pragma unroll
    for (int j = 0; j < 4; ++j)
      Out[(size_t)(r0 + lgrp * 4 + j) * 128 + col] = outacc[ot][j] + b2v;
  }
}

// ---------------------------------------------------------------------------
extern "C" void kernel_launch(void* const* d_in, const int* in_sizes, int n_in,
                              void* d_out, int out_size, void* d_ws, size_t ws_size,
                              hipStream_t stream) {
  const float* Xu = (const float*)d_in[0];
  const float* Xv = (const float*)d_in[1];
  const float* Xe = (const float*)d_in[2];
  const float* Wn = (const float*)d_in[3];
  const float* bn = (const float*)d_in[4];
  const float* We = (const float*)d_in[5];
  const float* be = (const float*)d_in[6];
  const float* Wi = (const float*)d_in[7];
  const float* bi = (const float*)d_in[8];
  const float* Wo = (const float*)d_in[9];
  const float* bo = (const float*)d_in[10];
  const float* W1 = (const float*)d_in[11];
  const float* b1 = (const float*)d_in[12];
  const float* W2 = (const float*)d_in[13];
  const float* b2 = (const float*)d_in[14];

  // ws layout, NO aliasing; total EXACTLY 2,753,536 B (= R5/R8-proven ceiling).
  char* ws = (char*)d_ws;
  float* FT = (float*)(ws + 0);                            // [128,512] f32   262144 B
  float* P  = (float*)(ws + 262144);                       // [256,512] f32   524288 B
  float* Kn = (float*)(ws + 786432);                       // [2][256,256]    524288 B
  float* Ke = (float*)(ws + 1310720);                      // [2][256,128]    262144 B
  unsigned short* QmT  = (unsigned short*)(ws + 1572864);  // 262144 bf16     524288 B
  unsigned short* WnvT = (unsigned short*)(ws + 2097152);  // 131072 bf16     262144 B
  unsigned short* WevT = (unsigned short*)(ws + 2359296);  // 65536 bf16      131072 B
  unsigned short* MtnT = (unsigned short*)(ws + 2490368);  // 65536 bf16      131072 B
  unsigned short* MteT = (unsigned short*)(ws + 2621440);  // 32768 bf16       65536 B
  unsigned short* W2bT = (unsigned short*)(ws + 2686976);  // 32768 bf16       65536 B
  float* c2 = (float*)(ws + 2752512);                      // [256] f32         1024 B

  prep1<<<320, 256, 0, stream>>>(Wn, We, Wi, Wo, W1, W2, FT, P, Kn, Ke, WnvT, WevT, W2bT);
  prep2<<<89, 256, 0, stream>>>(Wi, W1, bi, bo, b1, FT, P, Kn, Ke, MtnT, MteT, QmT, c2);
  fused_kernel<<<512, 256, 0, stream>>>(Xu, Xv, Xe, bn, be, b2, MtnT, MteT, WnvT, WevT, QmT, W2bT,
                                        c2, (float*)d_out);
}

// Round 11
// 181.048 us; speedup vs baseline: 1.3472x; 1.0319x over previous
//
#include <hip/hip_runtime.h>

// MiniAttentionLayer fused kernel for MI355X (gfx950).
//
// ROUND 11: spill elimination. R10's launch_bounds(256,2) doubled occupancy
// (11->20%, 145->122us) but spilled (~37MB scratch WRITE): peak liveness
// 80 persistent + 28 prefetch batch + 12 accs + addr > 128 arch VGPRs.
// FIX (phase 2 only, protocol-preserving): parity-explicit loop; Wnv/Wev
// (12 regs) written right after v-GEMM on both parities (nb's Wnv/Wev slots
// are never read in-iteration); Qm batch (16 regs) loaded AFTER that write
// and held only across combine/Q-GEMM (Q-GEMM's 32 MFMA covers its latency).
// Peak transient 28 -> 16. Everything else R10 VERBATIM.
//
//   score[h,s]*16 = x_e^T M_{h,s} x_s ; softmax -> attn
//   M^n_h = F_h^T @ (Wk_h @ Wn_k) ; M^e_h = F_h^T @ (Wk_h @ We_k) ; F = Wq@We_q
//   vbar_h = sum_s attn[h,s] v_s ; v_s = W*_v x_s (+ b*_v)
//   h1pre = Qm @ [vbar_0|vbar_1] + c2 ; Qm_h = P @ Wv_h ; P = W1@Wo
//   out = W2 @ silu(h1pre) + b2

#define TPB 256

typedef __attribute__((ext_vector_type(8))) short bf16x8;
typedef __attribute__((ext_vector_type(4))) float f32x4;

__device__ __forceinline__ unsigned short f2bf(float f) {
  union { float f; unsigned u; } v; v.f = f;
  unsigned r = v.u + 0x7FFFu + ((v.u >> 16) & 1u);  // RNE
  return (unsigned short)(r >> 16);
}
__device__ __forceinline__ float bf2f(unsigned short h) {
  union { unsigned u; float f; } v; v.u = ((unsigned)h) << 16;
  return v.f;
}
__device__ __forceinline__ f32x4 mfma16(bf16x8 a, bf16x8 b, f32x4 c) {
  return __builtin_amdgcn_mfma_f32_16x16x32_bf16(a, b, c, 0, 0, 0);
}
__device__ __forceinline__ bf16x8 pack8(const float* __restrict__ p) {
  float4 a = *(const float4*)p;
  float4 b = *(const float4*)(p + 4);
  bf16x8 r;
  r[0] = (short)f2bf(a.x); r[1] = (short)f2bf(a.y);
  r[2] = (short)f2bf(a.z); r[3] = (short)f2bf(a.w);
  r[4] = (short)f2bf(b.x); r[5] = (short)f2bf(b.y);
  r[6] = (short)f2bf(b.z); r[7] = (short)f2bf(b.w);
  return r;
}
// fragment-tiled offset: element (lr = B-col within 16-tile, k) -> tiled index
__device__ __forceinline__ int fragoff(int lr, int k) {
  return (k >> 5) * 512 + ((k >> 3) & 3) * 128 + lr * 8 + (k & 7);
}

// GEMM micro-tile: 4m x 4n, 16 outputs/thread, all-float4 loads.
__device__ __forceinline__ void gemm44(const float* __restrict__ A0, int lda,
                                       const float* __restrict__ B0, int ldb,
                                       int K, float (&acc)[4][4]) {
  for (int k = 0; k < K; k += 4) {
    float a_[4][4], b_[4][4];
#pragma unroll
    for (int mi = 0; mi < 4; ++mi) {
      float4 t = *(const float4*)(A0 + mi * lda + k);
      a_[mi][0] = t.x; a_[mi][1] = t.y; a_[mi][2] = t.z; a_[mi][3] = t.w;
    }
#pragma unroll
    for (int kk = 0; kk < 4; ++kk) {
      float4 t = *(const float4*)(B0 + (size_t)(k + kk) * ldb);
      b_[kk][0] = t.x; b_[kk][1] = t.y; b_[kk][2] = t.z; b_[kk][3] = t.w;
    }
#pragma unroll
    for (int mi = 0; mi < 4; ++mi)
#pragma unroll
      for (int kk = 0; kk < 4; ++kk)
#pragma unroll
        for (int ni = 0; ni < 4; ++ni)
          acc[mi][ni] += a_[mi][kk] * b_[kk][ni];
  }
}

// ---------------------------------------------------------------------------
// prep1: F->FT ; P = W1@Wo ; Kn_h = Wk_h@Wn_k ; Ke_h = Wk_h@We_k ;
//        WnvT/WevT/W2bT tiled bf16 casts.  (R10 VERBATIM)
// ---------------------------------------------------------------------------
__global__ void prep1(const float* __restrict__ Wn, const float* __restrict__ We,
                      const float* __restrict__ Wi, const float* __restrict__ Wo,
                      const float* __restrict__ W1, const float* __restrict__ W2,
                      float* __restrict__ FT, float* __restrict__ P,
                      float* __restrict__ Kn, float* __restrict__ Ke,
                      unsigned short* __restrict__ WnvT, unsigned short* __restrict__ WevT,
                      unsigned short* __restrict__ W2bT) {
  const int bid = blockIdx.x, tid = threadIdx.x;
  const int tm = tid >> 5, tn = tid & 31;   // 8 x 32 thread tile
  if (bid < 16) {                           // F [512 m, 128 n] K=512 -> FT[n][m]
    int m = bid * 32 + tm * 4, n0 = tn * 4;
    float acc[4][4] = {};
    gemm44(Wi + m * 512, 512, We + n0, 128, 512, acc);
#pragma unroll
    for (int mi = 0; mi < 4; ++mi)
#pragma unroll
      for (int ni = 0; ni < 4; ++ni) FT[(n0 + ni) * 512 + m + mi] = acc[mi][ni];
  } else if (bid < 48) {                    // P [256 m, 512 n] K=512
    int b = bid - 16; int m = (b >> 2) * 32 + tm * 4, n0 = (b & 3) * 128 + tn * 4;
    float acc[4][4] = {};
    gemm44(W1 + m * 512, 512, Wo + n0, 512, 512, acc);
#pragma unroll
    for (int mi = 0; mi < 4; ++mi)
#pragma unroll
      for (int ni = 0; ni < 4; ++ni) P[(m + mi) * 512 + n0 + ni] = acc[mi][ni];
  } else if (bid < 80) {                    // Kn_h [256 c, 256 b] K=512
    int b = bid - 48; int h = b >> 4, r = b & 15;
    int c = (r >> 1) * 32 + tm * 4, b0 = (r & 1) * 128 + tn * 4;
    float acc[4][4] = {};
    gemm44(Wi + (size_t)(512 + h * 256 + c) * 512, 512, Wn + 512 * 256 + b0, 256, 512, acc);
#pragma unroll
    for (int mi = 0; mi < 4; ++mi)
#pragma unroll
      for (int ni = 0; ni < 4; ++ni) Kn[h * 65536 + (c + mi) * 256 + b0 + ni] = acc[mi][ni];
  } else if (bid < 96) {                    // Ke_h [256 c, 128 b] K=512
    int b = bid - 80; int h = b >> 3, r = b & 7;
    int c = r * 32 + tm * 4, b0 = tn * 4;
    float acc[4][4] = {};
    gemm44(Wi + (size_t)(512 + h * 256 + c) * 512, 512, We + 512 * 128 + b0, 128, 512, acc);
#pragma unroll
    for (int mi = 0; mi < 4; ++mi)
#pragma unroll
      for (int ni = 0; ni < 4; ++ni) Ke[h * 32768 + (c + mi) * 128 + b0 + ni] = acc[mi][ni];
  } else if (bid < 224) {                   // Wn_v -> bf16 TILED
    int i = ((bid - 96) * 256 + tid) * 4;
#pragma unroll
    for (int t = 0; t < 4; ++t) {
      int ii = i + t; int vrow = ii >> 8, k = ii & 255;
      WnvT[(vrow >> 4) * 4096 + fragoff(vrow & 15, k)] = f2bf(Wn[262144 + ii]);
    }
  } else if (bid < 288) {                   // We_v -> bf16 TILED
    int i = ((bid - 224) * 256 + tid) * 4;
#pragma unroll
    for (int t = 0; t < 4; ++t) {
      int ii = i + t; int vrow = ii >> 7, k = ii & 127;
      WevT[(vrow >> 4) * 2048 + fragoff(vrow & 15, k)] = f2bf(We[131072 + ii]);
    }
  } else {                                  // W2 -> bf16 TILED
    int i = ((bid - 288) * 256 + tid) * 4;
#pragma unroll
    for (int t = 0; t < 4; ++t) {
      int ii = i + t; int o = ii >> 8, k = ii & 255;
      W2bT[(k >> 6) * 8192 + ((k >> 5) & 1) * 4096 + (o >> 4) * 512 + fragoff(o & 15, k & 31)] =
          f2bf(W2[ii]);
    }
  }
}

// ---------------------------------------------------------------------------
// prep2: MtnT = F_h^T@Kn_h ; MteT = F_h^T@Ke_h ; QmT_h = P_h@Wv_h ; c2.
//        (R10 VERBATIM)
// ---------------------------------------------------------------------------
__global__ void prep2(const float* __restrict__ Wi, const float* __restrict__ W1,
                      const float* __restrict__ bi, const float* __restrict__ bo,
                      const float* __restrict__ b1,
                      const float* __restrict__ FT, const float* __restrict__ P,
                      const float* __restrict__ Kn, const float* __restrict__ Ke,
                      unsigned short* __restrict__ MtnT, unsigned short* __restrict__ MteT,
                      unsigned short* __restrict__ QmT, float* __restrict__ c2) {
  const int bid = blockIdx.x, tid = threadIdx.x;
  const int tm = tid >> 5, tn = tid & 31;
  if (bid < 16) {                           // Mtn_h [128 a, 256 b] K=256
    int h = bid >> 3, r = bid & 7;
    int a = (r >> 1) * 32 + tm * 4, b0 = (r & 1) * 128 + tn * 4;
    float acc[4][4] = {};
    gemm44(FT + a * 512 + h * 256, 512, Kn + h * 65536 + b0, 256, 256, acc);
#pragma unroll
    for (int mi = 0; mi < 4; ++mi)
#pragma unroll
      for (int ni = 0; ni < 4; ++ni) {
        int aa = a + mi, bb = b0 + ni;
        MtnT[(h * 2 + (bb >> 7)) * 16384 + ((bb >> 5) & 3) * 4096 + ((bb >> 4) & 1) * 2048 +
             fragoff(bb & 15, aa)] = f2bf(acc[mi][ni]);
      }
  } else if (bid < 24) {                    // Mte_h [128 a, 128 b] K=256
    int b = bid - 16; int h = b >> 2, r = b & 3;
    int a = r * 32 + tm * 4, b0 = tn * 4;
    float acc[4][4] = {};
    gemm44(FT + a * 512 + h * 256, 512, Ke + h * 32768 + b0, 128, 256, acc);
#pragma unroll
    for (int mi = 0; mi < 4; ++mi)
#pragma unroll
      for (int ni = 0; ni < 4; ++ni) {
        int aa = a + mi, bb = b0 + ni;
        MteT[h * 16384 + ((bb >> 5) & 3) * 4096 + ((bb >> 4) & 1) * 2048 +
             fragoff(bb & 15, aa)] = f2bf(acc[mi][ni]);
      }
  } else if (bid < 88) {                    // Qm_h [256 i, 512 t] K=256
    int b = bid - 24; int h = b >> 5, r = b & 31;
    int i = (r >> 2) * 32 + tm * 4, t0 = (r & 3) * 128 + tn * 4;
    float acc[4][4] = {};
    gemm44(P + i * 512 + h * 256, 512, Wi + (size_t)(1024 + h * 256) * 512 + t0, 512, 256, acc);
#pragma unroll
    for (int mi = 0; mi < 4; ++mi)
#pragma unroll
      for (int ni = 0; ni < 4; ++ni) {
        int ii = i + mi, tt = t0 + ni;
        QmT[(tt >> 5) * 16384 + h * 8192 + (ii >> 4) * 512 + fragoff(ii & 15, tt & 31)] =
            f2bf(acc[mi][ni]);
      }
  } else {                                  // c2: b1 + P@bv + W1@bo (one block)
    float cc = b1[tid];
    for (int c = 0; c < 512; ++c) cc += P[tid * 512 + c] * bi[1024 + c] + W1[tid * 512 + c] * bo[c];
    c2[tid] = cc;
  }
}

// ---------------------------------------------------------------------------
// Fused kernel helpers (R10 VERBATIM)
// ---------------------------------------------------------------------------
__device__ __forceinline__ void stage32k(unsigned short* lds, const unsigned short* __restrict__ src,
                                         int tid) {
#pragma unroll
  for (int i = 0; i < 8; ++i) {
    int seg = i * 256 + tid;
    *(int4*)(lds + seg * 8) = *(const int4*)(src + seg * 8);
  }
}

template <int AOFS>
__device__ __forceinline__ void p1n(const unsigned short* __restrict__ srcT,
                                    unsigned short* sflat, unsigned short (&tb)[16][40],
                                    const bf16x8 (&au)[8], const bf16x8 (&av)[8],
                                    const bf16x8 (&ae)[4], int tid, int lrow, int lgrp,
                                    float& su, float& sv) {
  stage32k(sflat, srcT, tid);
  __syncthreads();
  const int lane8 = (lgrp * 16 + lrow) * 8;
#pragma unroll
  for (int c = 0; c < 4; ++c) {
    f32x4 acc0 = {0.f, 0.f, 0.f, 0.f}, acc1 = {0.f, 0.f, 0.f, 0.f};
#pragma unroll
    for (int kt = 0; kt < 4; ++kt) {
      bf16x8 b0 = *(bf16x8*)(sflat + c * 4096 + kt * 512 + lane8);
      bf16x8 b1f = *(bf16x8*)(sflat + c * 4096 + 2048 + kt * 512 + lane8);
      acc0 = mfma16(ae[kt], b0, acc0);
      acc1 = mfma16(ae[kt], b1f, acc1);
    }
#pragma unroll
    for (int j = 0; j < 4; ++j) {
      tb[lgrp * 4 + j][lrow] = f2bf(acc0[j]);
      tb[lgrp * 4 + j][16 + lrow] = f2bf(acc1[j]);
    }
    bf16x8 y = *(bf16x8*)&tb[lrow][lgrp * 8];
#pragma unroll
    for (int j = 0; j < 8; ++j) {
      float yf = bf2f((unsigned short)y[j]);
      su += yf * bf2f((unsigned short)au[AOFS + c][j]);
      sv += yf * bf2f((unsigned short)av[AOFS + c][j]);
    }
  }
  __syncthreads();
}

__device__ __forceinline__ void p1e(const unsigned short* __restrict__ srcT,
                                    unsigned short* sflat, unsigned short (&tb)[16][40],
                                    const bf16x8 (&ae)[4], int tid, int lrow, int lgrp,
                                    float& se) {
  stage32k(sflat, srcT, tid);
  __syncthreads();
  const int lane8 = (lgrp * 16 + lrow) * 8;
#pragma unroll
  for (int c = 0; c < 4; ++c) {
    f32x4 acc0 = {0.f, 0.f, 0.f, 0.f}, acc1 = {0.f, 0.f, 0.f, 0.f};
#pragma unroll
    for (int kt = 0; kt < 4; ++kt) {
      bf16x8 b0 = *(bf16x8*)(sflat + c * 4096 + kt * 512 + lane8);
      bf16x8 b1f = *(bf16x8*)(sflat + c * 4096 + 2048 + kt * 512 + lane8);
      acc0 = mfma16(ae[kt], b0, acc0);
      acc1 = mfma16(ae[kt], b1f, acc1);
    }
#pragma unroll
    for (int j = 0; j < 4; ++j) {
      tb[lgrp * 4 + j][lrow] = f2bf(acc0[j]);
      tb[lgrp * 4 + j][16 + lrow] = f2bf(acc1[j]);
    }
    bf16x8 y = *(bf16x8*)&tb[lrow][lgrp * 8];
#pragma unroll
    for (int j = 0; j < 8; ++j)
      se += bf2f((unsigned short)y[j]) * bf2f((unsigned short)ae[c][j]);
  }
  __syncthreads();
}

// ---------------------------------------------------------------------------
// Fused main kernel: 512 blocks x 256 threads (4 waves x 16 rows).
// launch_bounds(256,2); phase-2 loop parity-split for low register liveness.
// ---------------------------------------------------------------------------
__global__ __launch_bounds__(TPB, 2) void fused_kernel(
    const float* __restrict__ Xu, const float* __restrict__ Xv, const float* __restrict__ Xe,
    const float* __restrict__ bn, const float* __restrict__ be, const float* __restrict__ b2,
    const unsigned short* __restrict__ MtnT, const unsigned short* __restrict__ MteT,
    const unsigned short* __restrict__ WnvT, const unsigned short* __restrict__ WevT,
    const unsigned short* __restrict__ QmT, const unsigned short* __restrict__ W2bT,
    const float* __restrict__ c2, float* __restrict__ Out) {
  // buf b at sStage + b*14336: Wnv[0,4096) Wev[4096,6144) Qm-half[6144,14336)
  __shared__ unsigned short sStage[28672];          // 56 KB
  __shared__ unsigned short sTbuf[4][2][16][40];    // 10 KB wave-local bounce
  __shared__ float sAttn[4][16][8];                 // 2 KB

  const int tid = threadIdx.x;
  const int wave = tid >> 6;
  const int lane = tid & 63;
  const int lrow = lane & 15, lgrp = lane >> 4;
  const int lane8 = lane * 8;
  const int r0 = blockIdx.x * 64 + wave * 16;

  // ---- A fragments (rows of this wave), fp32 -> bf16 ----
  bf16x8 au[8], av[8], ae[4];
  {
    const float* xu = Xu + (size_t)(r0 + lrow) * 256;
    const float* xv = Xv + (size_t)(r0 + lrow) * 256;
    const float* xe = Xe + (size_t)(r0 + lrow) * 128;
#pragma unroll
    for (int kt = 0; kt < 8; ++kt) {
      int off = kt * 32 + lgrp * 8;
      au[kt] = pack8(xu + off);
      av[kt] = pack8(xv + off);
    }
#pragma unroll
    for (int kt = 0; kt < 4; ++kt) ae[kt] = pack8(xe + kt * 32 + lgrp * 8);
  }

  // ================= Phase 1: scores (6 staged 32KB slices) =================
  float su0 = 0.f, sv0 = 0.f, se0 = 0.f, su1 = 0.f, sv1 = 0.f, se1 = 0.f;
  p1n<0>(MtnT,          sStage, sTbuf[wave][0], au, av, ae, tid, lrow, lgrp, su0, sv0);
  p1n<4>(MtnT + 16384,  sStage, sTbuf[wave][0], au, av, ae, tid, lrow, lgrp, su0, sv0);
  p1n<0>(MtnT + 32768,  sStage, sTbuf[wave][0], au, av, ae, tid, lrow, lgrp, su1, sv1);
  p1n<4>(MtnT + 49152,  sStage, sTbuf[wave][0], au, av, ae, tid, lrow, lgrp, su1, sv1);
  p1e(MteT,          sStage, sTbuf[wave][0], ae, tid, lrow, lgrp, se0);
  p1e(MteT + 16384,  sStage, sTbuf[wave][0], ae, tid, lrow, lgrp, se1);

  su0 += __shfl_xor(su0, 16); su0 += __shfl_xor(su0, 32);
  sv0 += __shfl_xor(sv0, 16); sv0 += __shfl_xor(sv0, 32);
  se0 += __shfl_xor(se0, 16); se0 += __shfl_xor(se0, 32);
  su1 += __shfl_xor(su1, 16); su1 += __shfl_xor(su1, 32);
  sv1 += __shfl_xor(sv1, 16); sv1 += __shfl_xor(sv1, 32);
  se1 += __shfl_xor(se1, 16); se1 += __shfl_xor(se1, 32);
  if (lane < 16) {
    sAttn[wave][lrow][0] = su0; sAttn[wave][lrow][1] = sv0; sAttn[wave][lrow][2] = se0;
    sAttn[wave][lrow][3] = su1; sAttn[wave][lrow][4] = sv1; sAttn[wave][lrow][5] = se1;
  }
  // softmax over s (scale 1/16); wave-local
  if (lane < 16) {
#pragma unroll
    for (int h = 0; h < 2; ++h) {
      float s0 = sAttn[wave][lrow][h * 3 + 0] * 0.0625f;
      float s1 = sAttn[wave][lrow][h * 3 + 1] * 0.0625f;
      float s2 = sAttn[wave][lrow][h * 3 + 2] * 0.0625f;
      float m = fmaxf(s0, fmaxf(s1, s2));
      float e0 = __expf(s0 - m), e1 = __expf(s1 - m), e2 = __expf(s2 - m);
      float inv = 1.f / (e0 + e1 + e2);
      sAttn[wave][lrow][h * 3 + 0] = e0 * inv;
      sAttn[wave][lrow][h * 3 + 1] = e1 * inv;
      sAttn[wave][lrow][h * 3 + 2] = e2 * inv;
    }
  }

  // ================= Phase 2: v-GEMM + vbar + Q-GEMM, 32 chunks =============
  f32x4 h1acc[16];
#pragma unroll
  for (int i = 0; i < 16; ++i) h1acc[i] = (f32x4){0.f, 0.f, 0.f, 0.f};

  // prologue: buf0 = {Wnv(0), Wev(0), Qm pair0 half1}
  {
#pragma unroll
    for (int i = 0; i < 7; ++i) {
      int seg = i * 256 + tid;
      int4 v;
      if (i < 2)       v = *(const int4*)(WnvT + seg * 8);
      else if (i == 2) v = *(const int4*)(WevT + (seg - 512) * 8);
      else             v = *(const int4*)(QmT + 8192 + (seg - 768) * 8);
      *(int4*)(sStage + seg * 8) = v;
    }
  }
  __syncthreads();

#pragma unroll 1
  for (int t2 = 0; t2 < 16; ++t2) {
    // ========== EVEN t = 2*t2 : wb = buf0, nb = buf1 ==========
    {
      const int t = 2 * t2;
      unsigned short* wb = sStage;
      unsigned short* nb = sStage + 14336;
      const int cn = t + 1;                 // next chunk (<=31)
      // stage A: Wnv/Wev of chunk t+1 (12 regs)
      int4 st0 = *(const int4*)(WnvT + cn * 4096 + tid * 8);
      int4 st1 = *(const int4*)(WnvT + cn * 4096 + (256 + tid) * 8);
      int4 st2 = *(const int4*)(WevT + cn * 2048 + tid * 8);

      // v-GEMM on wb
      f32x4 vu = {0.f, 0.f, 0.f, 0.f}, vv = {0.f, 0.f, 0.f, 0.f}, ve = {0.f, 0.f, 0.f, 0.f};
#pragma unroll
      for (int kt = 0; kt < 8; ++kt) {
        bf16x8 b = *(bf16x8*)(wb + kt * 512 + lane8);
        vu = mfma16(au[kt], b, vu);
        vv = mfma16(av[kt], b, vv);
      }
#pragma unroll
      for (int kt = 0; kt < 4; ++kt) {
        bf16x8 b = *(bf16x8*)(wb + 4096 + kt * 512 + lane8);
        ve = mfma16(ae[kt], b, ve);
      }
      // write Wnv/Wev -> nb (buf1 is read by nobody during even t)
      *(int4*)(nb + tid * 8) = st0;
      *(int4*)(nb + (256 + tid) * 8) = st1;
      *(int4*)(nb + (512 + tid) * 8) = st2;

      // stage B: Qm pair t2 half0 (16 regs; latency covered by combine)
      const int qoff = t2 * 16384;
      int4 st3 = *(const int4*)(QmT + qoff + tid * 8);
      int4 st4 = *(const int4*)(QmT + qoff + (256 + tid) * 8);
      int4 st5 = *(const int4*)(QmT + qoff + (512 + tid) * 8);
      int4 st6 = *(const int4*)(QmT + qoff + (768 + tid) * 8);

      // combine -> sTbuf (cur=0 -> col offset 0)
      const int vrow = t * 16 + lrow;
      const float bnv = bn[1024 + vrow], bev = be[1024 + vrow];
#pragma unroll
      for (int j = 0; j < 4; ++j) {
        const float* ar = &sAttn[wave][lgrp * 4 + j][0];
#pragma unroll
        for (int h = 0; h < 2; ++h) {
          float a0 = ar[h * 3 + 0], a1 = ar[h * 3 + 1], a2 = ar[h * 3 + 2];
          float vb = a0 * vu[j] + a1 * vv[j] + a2 * ve[j] + (a0 + a1) * bnv + a2 * bev;
          sTbuf[wave][h][lgrp * 4 + j][lrow] = f2bf(vb);
        }
      }
      // write Qm -> nb
      *(int4*)(nb + (768 + tid) * 8) = st3;
      *(int4*)(nb + (1024 + tid) * 8) = st4;
      *(int4*)(nb + (1280 + tid) * 8) = st5;
      *(int4*)(nb + (1536 + tid) * 8) = st6;
      __syncthreads();
    }
    // ========== ODD t = 2*t2+1 : wb = buf1, nb = buf0 ==========
    {
      const int t = 2 * t2 + 1;
      unsigned short* wb = sStage + 14336;
      unsigned short* nb = sStage;
      const bool last = (t2 == 15);
      const int cn = t + 1;

      // stage A: Wnv/Wev of chunk t+1 (skip on last)
      int4 st0, st1, st2;
      if (!last) {
        st0 = *(const int4*)(WnvT + cn * 4096 + tid * 8);
        st1 = *(const int4*)(WnvT + cn * 4096 + (256 + tid) * 8);
        st2 = *(const int4*)(WevT + cn * 2048 + tid * 8);
      }

      // v-GEMM on wb
      f32x4 vu = {0.f, 0.f, 0.f, 0.f}, vv = {0.f, 0.f, 0.f, 0.f}, ve = {0.f, 0.f, 0.f, 0.f};
#pragma unroll
      for (int kt = 0; kt < 8; ++kt) {
        bf16x8 b = *(bf16x8*)(wb + kt * 512 + lane8);
        vu = mfma16(au[kt], b, vu);
        vv = mfma16(av[kt], b, vv);
      }
#pragma unroll
      for (int kt = 0; kt < 4; ++kt) {
        bf16x8 b = *(bf16x8*)(wb + 4096 + kt * 512 + lane8);
        ve = mfma16(ae[kt], b, ve);
      }
      // write Wnv/Wev -> nb (buf0's Wnv/Wev slots unread during odd t)
      if (!last) {
        *(int4*)(nb + tid * 8) = st0;
        *(int4*)(nb + (256 + tid) * 8) = st1;
        *(int4*)(nb + (512 + tid) * 8) = st2;
      }

      // stage B: Qm pair t2+1 half1 (latency covered by combine + Q-GEMM)
      int4 st3, st4, st5, st6;
      if (!last) {
        const int qoff = (t2 + 1) * 16384 + 8192;
        st3 = *(const int4*)(QmT + qoff + tid * 8);
        st4 = *(const int4*)(QmT + qoff + (256 + tid) * 8);
        st5 = *(const int4*)(QmT + qoff + (512 + tid) * 8);
        st6 = *(const int4*)(QmT + qoff + (768 + tid) * 8);
      }

      // combine -> sTbuf (cur=1 -> col offset 16)
      const int vrow = t * 16 + lrow;
      const float bnv = bn[1024 + vrow], bev = be[1024 + vrow];
#pragma unroll
      for (int j = 0; j < 4; ++j) {
        const float* ar = &sAttn[wave][lgrp * 4 + j][0];
#pragma unroll
        for (int h = 0; h < 2; ++h) {
          float a0 = ar[h * 3 + 0], a1 = ar[h * 3 + 1], a2 = ar[h * 3 + 2];
          float vb = a0 * vu[j] + a1 * vv[j] + a2 * ve[j] + (a0 + a1) * bnv + a2 * bev;
          sTbuf[wave][h][lgrp * 4 + j][16 + lrow] = f2bf(vb);
        }
      }

      // Q-GEMM over the completed 32-col pair: h2=0 from wb, h2=1 from nb
#pragma unroll
      for (int h2 = 0; h2 < 2; ++h2) {
        const unsigned short* qb = (h2 == 0 ? wb : nb) + 6144;
        bf16x8 vbx = *(bf16x8*)&sTbuf[wave][h2][lrow][lgrp * 8];
#pragma unroll
        for (int nt = 0; nt < 16; ++nt) {
          bf16x8 bq = *(bf16x8*)(qb + nt * 512 + lane8);
          h1acc[nt] = mfma16(vbx, bq, h1acc[nt]);
        }
      }
      __syncthreads();  // all waves done reading nb's Qm slot before overwrite
      if (!last) {
        *(int4*)(nb + (768 + tid) * 8) = st3;
        *(int4*)(nb + (1024 + tid) * 8) = st4;
        *(int4*)(nb + (1280 + tid) * 8) = st5;
        *(int4*)(nb + (1536 + tid) * 8) = st6;
      }
      __syncthreads();
    }
  }

  // ================= Phase 3: silu + W2 (2 staged 32KB halves) ==============
  f32x4 outacc[8];
#pragma unroll
  for (int i = 0; i < 8; ++i) outacc[i] = (f32x4){0.f, 0.f, 0.f, 0.f};

#pragma unroll
  for (int hh = 0; hh < 2; ++hh) {
    if (hh) __syncthreads();  // protect previous half's reads
    stage32k(sStage, W2bT + hh * 16384, tid);
    __syncthreads();
#pragma unroll
    for (int kc = 0; kc < 2; ++kc) {
      const int kg = hh * 2 + kc;
#pragma unroll
      for (int tt = 0; tt < 4; ++tt) {
        int nt = kg * 4 + tt;
        float c2v = c2[nt * 16 + lrow];
#pragma unroll
        for (int j = 0; j < 4; ++j) {
          float x = h1acc[nt][j] + c2v;
          float s = x / (1.f + __expf(-x));  // silu
          sTbuf[wave][tt >> 1][lgrp * 4 + j][(tt & 1) * 16 + lrow] = f2bf(s);
        }
      }
#pragma unroll
      for (int p = 0; p < 2; ++p) {
        bf16x8 hA = *(bf16x8*)&sTbuf[wave][p][lrow][lgrp * 8];
#pragma unroll
        for (int ot = 0; ot < 8; ++ot) {
          bf16x8 w2 = *(bf16x8*)(sStage + kc * 8192 + p * 4096 + ot * 512 + lane8);
          outacc[ot] = mfma16(hA, w2, outacc[ot]);
        }
      }
    }
  }

  // epilogue: out = outacc + b2 (fp32)
#pragma unroll
  for (int ot = 0; ot < 8; ++ot) {
    int col = ot * 16 + lrow;
    float b2v = b2[col];
#pragma unroll
    for (int j = 0; j < 4; ++j)
      Out[(size_t)(r0 + lgrp * 4 + j) * 128 + col] = outacc[ot][j] + b2v;
  }
}

// ---------------------------------------------------------------------------
extern "C" void kernel_launch(void* const* d_in, const int* in_sizes, int n_in,
                              void* d_out, int out_size, void* d_ws, size_t ws_size,
                              hipStream_t stream) {
  const float* Xu = (const float*)d_in[0];
  const float* Xv = (const float*)d_in[1];
  const float* Xe = (const float*)d_in[2];
  const float* Wn = (const float*)d_in[3];
  const float* bn = (const float*)d_in[4];
  const float* We = (const float*)d_in[5];
  const float* be = (const float*)d_in[6];
  const float* Wi = (const float*)d_in[7];
  const float* bi = (const float*)d_in[8];
  const float* Wo = (const float*)d_in[9];
  const float* bo = (const float*)d_in[10];
  const float* W1 = (const float*)d_in[11];
  const float* b1 = (const float*)d_in[12];
  const float* W2 = (const float*)d_in[13];
  const float* b2 = (const float*)d_in[14];

  // ws layout, NO aliasing; total EXACTLY 2,753,536 B (= R5/R8-proven ceiling).
  char* ws = (char*)d_ws;
  float* FT = (float*)(ws + 0);                            // [128,512] f32   262144 B
  float* P  = (float*)(ws + 262144);                       // [256,512] f32   524288 B
  float* Kn = (float*)(ws + 786432);                       // [2][256,256]    524288 B
  float* Ke = (float*)(ws + 1310720);                      // [2][256,128]    262144 B
  unsigned short* QmT  = (unsigned short*)(ws + 1572864);  // 262144 bf16     524288 B
  unsigned short* WnvT = (unsigned short*)(ws + 2097152);  // 131072 bf16     262144 B
  unsigned short* WevT = (unsigned short*)(ws + 2359296);  // 65536 bf16      131072 B
  unsigned short* MtnT = (unsigned short*)(ws + 2490368);  // 65536 bf16      131072 B
  unsigned short* MteT = (unsigned short*)(ws + 2621440);  // 32768 bf16       65536 B
  unsigned short* W2bT = (unsigned short*)(ws + 2686976);  // 32768 bf16       65536 B
  float* c2 = (float*)(ws + 2752512);                      // [256] f32         1024 B

  prep1<<<320, 256, 0, stream>>>(Wn, We, Wi, Wo, W1, W2, FT, P, Kn, Ke, WnvT, WevT, W2bT);
  prep2<<<89, 256, 0, stream>>>(Wi, W1, bi, bo, b1, FT, P, Kn, Ke, MtnT, MteT, QmT, c2);
  fused_kernel<<<512, 256, 0, stream>>>(Xu, Xv, Xe, bn, be, b2, MtnT, MteT, WnvT, WevT, QmT, W2bT,
                                        c2, (float*)d_out);
}